// Round 8
// baseline (893.904 us; speedup 1.0000x reference)
//
#include <hip/hip_runtime.h>
#include <hip/hip_bf16.h>
#include <cstddef>

#define N_NODES 131072
#define N_EDGES 1048576
#define NF 78
#define NB 512
#define BNR 0.9999950000374996f  // 1/sqrt(1+1e-5)

__device__ __forceinline__ float wave_red_sum(float v) {
  for (int off = 32; off > 0; off >>= 1) v += __shfl_down(v, off);
  return v;
}

__device__ __forceinline__ float bf2f(unsigned short u) {
  return __uint_as_float(((unsigned)u) << 16);
}

__device__ __forceinline__ unsigned f2bf_rn(float x) {  // round-to-nearest-even bf16 bits
  unsigned u = __float_as_uint(x);
  return (u + 0x7fffu + ((u >> 16) & 1u)) >> 16;
}

// ---------------- graph setup ----------------
__global__ void k_count(const int* __restrict__ dst, int* __restrict__ cnt) {
  int e = blockIdx.x * 256 + threadIdx.x;
  if (e < N_EDGES) atomicAdd(&cnt[dst[e]], 1);
}

__global__ void k_dis(const int* __restrict__ cnt, float* __restrict__ dis) {
  int n = blockIdx.x * 256 + threadIdx.x;
  if (n < N_NODES) dis[n] = rsqrtf(1.0f + (float)cnt[n]);
}

__global__ void k_scan1(const int* __restrict__ cnt, int* __restrict__ offs, int* __restrict__ bsum) {
  __shared__ int s[512];
  int gid = blockIdx.x * 512 + threadIdx.x;
  int v = cnt[gid];
  s[threadIdx.x] = v; __syncthreads();
  for (int off = 1; off < 512; off <<= 1) {
    int t = (threadIdx.x >= off) ? s[threadIdx.x - off] : 0;
    __syncthreads();
    s[threadIdx.x] += t;
    __syncthreads();
  }
  offs[gid] = s[threadIdx.x] - v;               // exclusive
  if (threadIdx.x == 511) bsum[blockIdx.x] = s[511];
}

__global__ void k_scan2(int* __restrict__ bsum) {  // 1 block, 256 threads
  __shared__ int s[256];
  int v = bsum[threadIdx.x];
  s[threadIdx.x] = v; __syncthreads();
  for (int off = 1; off < 256; off <<= 1) {
    int t = (threadIdx.x >= off) ? s[threadIdx.x - off] : 0;
    __syncthreads();
    s[threadIdx.x] += t;
    __syncthreads();
  }
  bsum[threadIdx.x] = s[threadIdx.x] - v;       // exclusive
}

__global__ void k_scan3(int* __restrict__ offs, const int* __restrict__ bsum) {
  int gid = blockIdx.x * 512 + threadIdx.x;
  offs[gid] += bsum[blockIdx.x];
}

__global__ void k_fill(const int* __restrict__ src, const int* __restrict__ dst,
                       const int* __restrict__ offs, int* __restrict__ cursor,
                       const float* __restrict__ dis, int* __restrict__ csr,
                       float* __restrict__ cf) {
  int e = blockIdx.x * 256 + threadIdx.x;
  if (e < N_EDGES) {
    int s = src[e], d = dst[e];
    int pos = offs[d] + atomicAdd(&cursor[d], 1);
    csr[pos] = s;
    cf[pos] = dis[s] * dis[d];
  }
}

// ---------------- GCN layer ----------------
// t = h @ W  (layer 1, f32 input, no gate), output bf16
__global__ __launch_bounds__(256) void k_gemm_f32(const float* __restrict__ h,
                                                  const float* __restrict__ W,
                                                  unsigned short* __restrict__ t) {
  __shared__ float hs[64 * NF];
  __shared__ float Ws[NF * NF];
  int n0 = blockIdx.x * 64;
  int tid = threadIdx.x;
  for (int i = tid; i < NF * NF; i += 256) Ws[i] = W[i];
  for (int i = tid; i < 64 * NF; i += 256) hs[i] = h[(size_t)n0 * NF + i];
  __syncthreads();
  int rg = tid >> 4, cg = tid & 15;
  int r0 = rg * 4, c0 = cg * 5;
  float acc[4][5] = {};
  for (int k = 0; k < NF; ++k) {
    float wv[5];
#pragma unroll
    for (int j = 0; j < 5; ++j) wv[j] = (c0 + j < NF) ? Ws[k * NF + c0 + j] : 0.f;
#pragma unroll
    for (int i = 0; i < 4; ++i) {
      float hv = hs[(r0 + i) * NF + k];
#pragma unroll
      for (int j = 0; j < 5; ++j) acc[i][j] += hv * wv[j];
    }
  }
  for (int i = 0; i < 4; ++i)
    for (int j = 0; j < 5; ++j) {
      int c = c0 + j;
      if (c < NF) t[(size_t)(n0 + r0 + i) * NF + c] = (unsigned short)f2bf_rn(acc[i][j]);
    }
}

// t = (h .* gate) @ W  (layers 2,3; h bf16), output bf16
__global__ __launch_bounds__(256) void k_gemm_bf16(const unsigned short* __restrict__ h,
                                                   const float* __restrict__ gate,
                                                   const float* __restrict__ W,
                                                   unsigned short* __restrict__ t) {
  __shared__ float hs[64 * NF];
  __shared__ float Ws[NF * NF];
  int n0 = blockIdx.x * 64;
  int tid = threadIdx.x;
  for (int i = tid; i < NF * NF; i += 256) Ws[i] = W[i];
  for (int i = tid; i < 64 * NF; i += 256) {
    int r = i / NF;
    hs[i] = bf2f(h[(size_t)n0 * NF + i]) * gate[n0 + r];
  }
  __syncthreads();
  int rg = tid >> 4, cg = tid & 15;
  int r0 = rg * 4, c0 = cg * 5;
  float acc[4][5] = {};
  for (int k = 0; k < NF; ++k) {
    float wv[5];
#pragma unroll
    for (int j = 0; j < 5; ++j) wv[j] = (c0 + j < NF) ? Ws[k * NF + c0 + j] : 0.f;
#pragma unroll
    for (int i = 0; i < 4; ++i) {
      float hv = hs[(r0 + i) * NF + k];
#pragma unroll
      for (int j = 0; j < 5; ++j) acc[i][j] += hv * wv[j];
    }
  }
  for (int i = 0; i < 4; ++i)
    for (int j = 0; j < 5; ++j) {
      int c = c0 + j;
      if (c < NF) t[(size_t)(n0 + r0 + i) * NF + c] = (unsigned short)f2bf_rn(acc[i][j]);
    }
}

// out = relu(bn(agg + t*selfc + b)); also spre = out . Wp  (one wave per node)
// Row = 39 uints (78 bf16). One global_load_dword per edge; lanes 39-63 clamp.
__global__ __launch_bounds__(256) void k_agg(const unsigned* __restrict__ tu, const int* __restrict__ offs,
                                             const int* __restrict__ cnt, const int* __restrict__ csr,
                                             const float* __restrict__ cf, const float* __restrict__ dis,
                                             const float* __restrict__ bias, const float* __restrict__ bn,
                                             const float* __restrict__ Wp,
                                             unsigned* __restrict__ hout, float* __restrict__ spre) {
  int wave = threadIdx.x >> 6, lane = threadIdx.x & 63;
  int n = blockIdx.x * 4 + wave;
  float disn = dis[n];
  int st = offs[n], cn = cnt[n];
  int cn1 = cn < 64 ? cn : 64;
  int sIdx = 0; float sCoef = 0.f;
  if (lane < cn1) {
    sIdx = csr[st + lane] * 39;
    sCoef = cf[st + lane];
  }
  int lc = lane < 39 ? lane : 38;
  int rowu = n * 39;
  float selfc = disn * disn;
  unsigned su = tu[rowu + lc];
  float a0e = __uint_as_float(su << 16) * selfc;
  float a1e = __uint_as_float(su & 0xffff0000u) * selfc;
  float a0o = 0.f, a1o = 0.f;
  int j = 0;
#pragma unroll 4
  for (; j + 2 <= cn1; j += 2) {
    int sb0 = __shfl(sIdx, j);     float c0 = __shfl(sCoef, j);
    int sb1 = __shfl(sIdx, j + 1); float c1 = __shfl(sCoef, j + 1);
    unsigned u0 = tu[sb0 + lc];
    unsigned u1 = tu[sb1 + lc];
    a0e += c0 * __uint_as_float(u0 << 16);
    a1e += c0 * __uint_as_float(u0 & 0xffff0000u);
    a0o += c1 * __uint_as_float(u1 << 16);
    a1o += c1 * __uint_as_float(u1 & 0xffff0000u);
  }
  if (j < cn1) {
    int sb = __shfl(sIdx, j); float c = __shfl(sCoef, j);
    unsigned u = tu[sb + lc];
    a0e += c * __uint_as_float(u << 16);
    a1e += c * __uint_as_float(u & 0xffff0000u);
  }
  for (j = 64; j < cn; ++j) {  // safety tail, effectively never taken
    int sb = csr[st + j] * 39; float c = cf[st + j];
    unsigned u = tu[sb + lc];
    a0e += c * __uint_as_float(u << 16);
    a1e += c * __uint_as_float(u & 0xffff0000u);
  }
  float a0 = a0e + a0o, a1 = a1e + a1o;
  float h0 = 0.f, h1 = 0.f;
  float2 wp = make_float2(0.f, 0.f);
  if (lane < 39) {
    float2 bi = *reinterpret_cast<const float2*>(bias + 2 * lane);
    float2 gm = *reinterpret_cast<const float2*>(bn + 2 * lane);
    float2 bt = *reinterpret_cast<const float2*>(bn + NF + 2 * lane);
    h0 = fmaxf(0.f, gm.x * BNR * (a0 + bi.x) + bt.x);
    h1 = fmaxf(0.f, gm.y * BNR * (a1 + bi.y) + bt.y);
    hout[rowu + lane] = f2bf_rn(h0) | (f2bf_rn(h1) << 16);
    wp = *reinterpret_cast<const float2*>(Wp + 2 * lane);
  }
  float p = h0 * wp.x + h1 * wp.y;
  p = wave_red_sum(p);
  if (lane == 0) spre[n] = p;
}

__global__ void k_gate(const float* __restrict__ spre, const int* __restrict__ offs,
                       const int* __restrict__ cnt, const int* __restrict__ csr,
                       const float* __restrict__ cf, const float* __restrict__ dis,
                       const float* __restrict__ bp, float* __restrict__ gate) {
  int n = blockIdx.x * 256 + threadIdx.x;
  if (n >= N_NODES) return;
  float disn = dis[n];
  float s = bp[0] + disn * disn * spre[n];
  int st = offs[n], cn = cnt[n];
#pragma unroll 4
  for (int j = 0; j < cn; ++j) {
    s += cf[st + j] * spre[csr[st + j]];
  }
  gate[n] = tanhf(s);
}

// per-graph max & mean over contiguous 256-node segments; accumulate x1+x2+x3
__global__ __launch_bounds__(128) void k_readout(const unsigned short* __restrict__ h,
                                                 const float* __restrict__ gate,
                                                 float* __restrict__ xsum, int accum) {
  __shared__ float gl[256];
  int b = blockIdx.x, tid = threadIdx.x;
  for (int i = tid; i < 256; i += 128) gl[i] = gate[b * 256 + i];
  __syncthreads();
  if (tid >= NF) return;
  float mx = -1e30f, sm = 0.f;
  const unsigned short* hp = h + (size_t)b * 256 * NF + tid;
  for (int nn = 0; nn < 256; ++nn) {
    float v = bf2f(hp[(size_t)nn * NF]) * gl[nn];
    mx = fmaxf(mx, v);
    sm += v;
  }
  float mean = sm * (1.f / 256.f);
  if (accum) {
    xsum[b * 156 + tid] += mx;
    xsum[b * 156 + NF + tid] += mean;
  } else {
    xsum[b * 156 + tid] = mx;
    xsum[b * 156 + NF + tid] = mean;
  }
}

// g = relu(bn4((x1+x2+x3) @ fcg1_W + fcg1_b))
__global__ __launch_bounds__(128) void k_fcg(const float* __restrict__ xsum, const float* __restrict__ W,
                                             const float* __restrict__ bias, const float* __restrict__ bn,
                                             float* __restrict__ g) {
  __shared__ float xs[156];
  int b = blockIdx.x, tid = threadIdx.x;
  for (int i = tid; i < 156; i += 128) xs[i] = xsum[b * 156 + i];
  __syncthreads();
  float acc = bias[tid];
  for (int i = 0; i < 156; ++i) acc += xs[i] * W[i * 128 + tid];
  g[b * 128 + tid] = fmaxf(0.f, bn[tid] * BNR * acc + bn[128 + tid]);
}

// ---------------- protein branch ----------------
// Wt[i*384 + oc*3 + k] = c1W[oc*3000 + i*3 + k]
__global__ void k_transpose_w(const float* __restrict__ c1W, float* __restrict__ Wt) {
  int idx = blockIdx.x * 256 + threadIdx.x;
  if (idx >= 384000) return;
  int i = idx / 384;
  int r = idx - i * 384;
  int oc = r / 3, k = r - oc * 3;
  Wt[idx] = c1W[oc * 3000 + i * 3 + k];
}

// conv1 via vocab bucketing.
// 2a: counting-sort positions by vocab (INT LDS atomics, native); border holds (v<<10)|i sorted by v.
// 2b: 6 waves x 64-col stripes; 64-wide register prefetch of border + __shfl broadcast so the
//     coalesced Wt row loads pipeline (no LDS->VMEM serial chain); bucket-end flush = plain ds_write.
// 3:  el padded to stride 132; 9x ds_read_b128 broadcast per v.
__global__ __launch_bounds__(512) void k_conv1(const float* __restrict__ Wt, const int* __restrict__ target,
                                               const float* __restrict__ emb, const float* __restrict__ c1b,
                                               const float* __restrict__ bnx, float* __restrict__ O) {
  __shared__ float G[26 * 384];
  __shared__ float el[26 * 132];
  __shared__ int tg[1000];
  __shared__ int border[1000];
  __shared__ int cnt26[26], boff[27], cur26[26];
  int b = blockIdx.x, tid = threadIdx.x;
  int lane = tid & 63;
  if (tid < 26) cnt26[tid] = 0;
  for (int i = tid; i < 26 * 132; i += 512) {
    int v = i / 132, hp = i - v * 132;
    el[i] = (hp >= 1 && hp <= 128) ? emb[v * 128 + hp - 1] : 0.f;
  }
  for (int i = tid; i < 1000; i += 512) tg[i] = target[b * 1000 + i];
  __syncthreads();
  for (int i = tid; i < 1000; i += 512) atomicAdd(&cnt26[tg[i]], 1);
  __syncthreads();
  if (tid == 0) {
    int run = 0;
    for (int v = 0; v < 26; ++v) { boff[v] = run; cur26[v] = run; run += cnt26[v]; }
    boff[26] = run;
  }
  __syncthreads();
  for (int i = tid; i < 1000; i += 512) {
    int v = tg[i];
    int slot = atomicAdd(&cur26[v], 1);
    border[slot] = (v << 10) | i;
  }
  __syncthreads();
  if (tid < 384) {
    float acc = 0.f;
    int curv = 0;
    for (int chunk = 0; chunk < 1000; chunk += 64) {
      int kk = chunk + lane;
      int pk = (kk < 1000) ? border[kk] : 0;
      int jmax = (1000 - chunk) < 64 ? (1000 - chunk) : 64;
      for (int j = 0; j < jmax; ++j) {
        int p = __shfl(pk, j);
        int pv = p >> 10, pi = p & 1023;
        if (pv != curv) {                       // wave-uniform, rare
          G[curv * 384 + tid] = acc;
          for (int z = curv + 1; z < pv; ++z) G[z * 384 + tid] = 0.f;
          acc = 0.f; curv = pv;
        }
        acc += Wt[(size_t)pi * 384 + tid];
      }
    }
    G[curv * 384 + tid] = acc;
    for (int z = curv + 1; z < 26; ++z) G[z * 384 + tid] = 0.f;
  }
  __syncthreads();
  int oc = tid & 127, q = tid >> 7;
  int h0 = q * 32;
  float acc[32];
#pragma unroll
  for (int j = 0; j < 32; ++j) acc[j] = 0.f;
  for (int v = 0; v < 26; ++v) {
    float g0 = G[v * 384 + oc * 3 + 0];
    float g1 = G[v * 384 + oc * 3 + 1];
    float g2 = G[v * 384 + oc * 3 + 2];
    float4 buf[9];
    const float4* ep = reinterpret_cast<const float4*>(&el[v * 132 + h0]);
#pragma unroll
    for (int r = 0; r < 9; ++r) buf[r] = ep[r];
    const float* bf = reinterpret_cast<const float*>(buf);
#pragma unroll
    for (int j = 0; j < 32; ++j)
      acc[j] += g0 * bf[j] + g1 * bf[j + 1] + g2 * bf[j + 2];
  }
  float bia = c1b[oc];
  float sc = bnx[oc] * BNR, bt = bnx[128 + oc];
  float* outp = O + (size_t)b * 16384 + oc * 128 + h0;
#pragma unroll
  for (int j = 0; j < 32; ++j) acc[j] = fmaxf(0.f, sc * (acc[j] + bia) + bt);
#pragma unroll
  for (int j = 0; j < 8; ++j)
    *reinterpret_cast<float4*>(outp + 4 * j) =
        make_float4(acc[4 * j], acc[4 * j + 1], acc[4 * j + 2], acc[4 * j + 3]);
}

__global__ __launch_bounds__(256) void k_conv2(const float* __restrict__ X, const float* __restrict__ W,
                                               const float* __restrict__ bias, const float* __restrict__ bnx,
                                               float* __restrict__ O) {
  __shared__ float xl[128 * 136];
  int b = blockIdx.x, tid = threadIdx.x;
  for (int i = tid; i < 128 * 32; i += 256) {
    int row = i >> 5, c4 = (i & 31) * 4;
    float4 v = *reinterpret_cast<const float4*>(X + (size_t)b * 16384 + row * 128 + c4);
    *reinterpret_cast<float4*>(&xl[row * 136 + 4 + c4]) = v;
  }
  if (tid < 128) { xl[tid * 136 + 3] = 0.f; xl[tid * 136 + 132] = 0.f; }
  __syncthreads();
  int oc = tid & 63, q = tid >> 6;
  int h0 = q * 32;
  float acc[32];
#pragma unroll
  for (int j = 0; j < 32; ++j) acc[j] = 0.f;
  const float* wp = W + oc * 384;
  for (int i = 0; i < 128; ++i) {
    float w0 = wp[i * 3], w1 = wp[i * 3 + 1], w2 = wp[i * 3 + 2];
    const float* xr = &xl[i * 136 + 3 + h0];
    float e0 = xr[0], e1 = xr[1];
#pragma unroll
    for (int j = 0; j < 32; ++j) {
      float e2 = xr[j + 2];
      acc[j] += w0 * e0 + w1 * e1 + w2 * e2;
      e0 = e1; e1 = e2;
    }
  }
  float bia = bias[oc], sc = bnx[oc] * BNR, bt = bnx[64 + oc];
  float* outp = O + (size_t)b * 8192 + oc * 128 + h0;
#pragma unroll
  for (int j = 0; j < 32; ++j) acc[j] = fmaxf(0.f, sc * (acc[j] + bia) + bt);
#pragma unroll
  for (int j = 0; j < 8; ++j)
    *reinterpret_cast<float4*>(outp + 4 * j) =
        make_float4(acc[4 * j], acc[4 * j + 1], acc[4 * j + 2], acc[4 * j + 3]);
}

__global__ __launch_bounds__(256) void k_conv3(const float* __restrict__ X, const float* __restrict__ W,
                                               const float* __restrict__ bias, const float* __restrict__ bnx,
                                               float* __restrict__ O) {
  __shared__ float xl[64 * 136];
  int b = blockIdx.x, tid = threadIdx.x;
  for (int i = tid; i < 64 * 32; i += 256) {
    int row = i >> 5, c4 = (i & 31) * 4;
    float4 v = *reinterpret_cast<const float4*>(X + (size_t)b * 8192 + row * 128 + c4);
    *reinterpret_cast<float4*>(&xl[row * 136 + 4 + c4]) = v;
  }
  if (tid < 64) { xl[tid * 136 + 3] = 0.f; xl[tid * 136 + 132] = 0.f; }
  __syncthreads();
  int oc = tid & 31, q = tid >> 5;  // 0..7
  int h0 = q * 16;
  float acc[16];
#pragma unroll
  for (int j = 0; j < 16; ++j) acc[j] = 0.f;
  const float* wp = W + oc * 192;
  for (int i = 0; i < 64; ++i) {
    float w0 = wp[i * 3], w1 = wp[i * 3 + 1], w2 = wp[i * 3 + 2];
    const float* xr = &xl[i * 136 + 3 + h0];
    float e0 = xr[0], e1 = xr[1];
#pragma unroll
    for (int j = 0; j < 16; ++j) {
      float e2 = xr[j + 2];
      acc[j] += w0 * e0 + w1 * e1 + w2 * e2;
      e0 = e1; e1 = e2;
    }
  }
  float bia = bias[oc], sc = bnx[oc] * BNR, bt = bnx[32 + oc];
  float* outp = O + (size_t)b * 4096 + oc * 128 + h0;
#pragma unroll
  for (int j = 0; j < 16; ++j) acc[j] = fmaxf(0.f, sc * (acc[j] + bia) + bt);
#pragma unroll
  for (int j = 0; j < 4; ++j)
    *reinterpret_cast<float4*>(outp + 4 * j) =
        make_float4(acc[4 * j], acc[4 * j + 1], acc[4 * j + 2], acc[4 * j + 3]);
}

// ---- fxt: [512,4096] @ [4096,128], K-split 8 ways for parallelism ----
__global__ __launch_bounds__(128) void k_fxt_part(const float* __restrict__ P, const float* __restrict__ W,
                                                  float* __restrict__ part) {
  __shared__ float pl[8 * 512];
  int bblk = blockIdx.x >> 3, kc = blockIdx.x & 7;
  int b0 = bblk * 8, tid = threadIdx.x;
  for (int i = tid; i < 8 * 512; i += 128) {
    int bb = i >> 9, k = i & 511;
    pl[i] = P[(size_t)(b0 + bb) * 4096 + kc * 512 + k];
  }
  __syncthreads();
  float acc[8] = {};
  const float* wp = W + (size_t)kc * 512 * 128 + tid;
  for (int k = 0; k < 512; ++k) {
    float w = wp[(size_t)k * 128];
#pragma unroll
    for (int bb = 0; bb < 8; ++bb) acc[bb] += pl[bb * 512 + k] * w;
  }
#pragma unroll
  for (int bb = 0; bb < 8; ++bb)
    part[((size_t)kc * 512 + b0 + bb) * 128 + tid] = acc[bb];
}

// xt = bn6(relu(sum_kc part + fxt_b))   (bn AFTER relu)
__global__ __launch_bounds__(256) void k_fxt_red(const float* __restrict__ part, const float* __restrict__ bias,
                                                 const float* __restrict__ bn, float* __restrict__ xt) {
  int idx = blockIdx.x * 256 + threadIdx.x;  // 512*128
  int j = idx & 127;
  float s = 0.f;
#pragma unroll
  for (int kc = 0; kc < 8; ++kc) s += part[(size_t)kc * 65536 + idx];
  xt[idx] = bn[j] * BNR * fmaxf(0.f, s + bias[j]) + bn[128 + j];
}

// xc1 = bn7(relu([g|xt] @ fc1W + fc1b)); grid 512 = (bblk 0..127)x(jb 0..3)
__global__ __launch_bounds__(256) void k_fc1(const float* __restrict__ g, const float* __restrict__ xt,
                                             const float* __restrict__ W, const float* __restrict__ bias,
                                             const float* __restrict__ bn, float* __restrict__ out) {
  __shared__ float al[4 * 256];
  int bblk = blockIdx.x >> 2, jb = blockIdx.x & 3;
  int b0 = bblk * 4, tid = threadIdx.x;
  int j = jb * 256 + tid;
  for (int i = tid; i < 4 * 256; i += 256) {
    int bb = i >> 8, c = i & 255;
    al[i] = (c < 128) ? g[(b0 + bb) * 128 + c] : xt[(b0 + bb) * 128 + c - 128];
  }
  __syncthreads();
  float acc[4] = {};
  for (int i = 0; i < 256; ++i) {
    float w = W[(size_t)i * 1024 + j];
#pragma unroll
    for (int bb = 0; bb < 4; ++bb) acc[bb] += al[bb * 256 + i] * w;
  }
  float bi = bias[j], sc = bn[j] * BNR, bt = bn[1024 + j];
#pragma unroll
  for (int bb = 0; bb < 4; ++bb)
    out[(size_t)(b0 + bb) * 1024 + j] = sc * fmaxf(0.f, acc[bb] + bi) + bt;
}

// xc2 = bn8(relu(xc1 @ fc2W + fc2b)); grid 256 = (bblk 0..127)x(jb 0..1)
__global__ __launch_bounds__(256) void k_fc2(const float* __restrict__ xc1, const float* __restrict__ W,
                                             const float* __restrict__ bias, const float* __restrict__ bn,
                                             float* __restrict__ out) {
  __shared__ float al[4 * 1024];
  int bblk = blockIdx.x >> 1, jb = blockIdx.x & 1;
  int b0 = bblk * 4, tid = threadIdx.x;
  int j = jb * 256 + tid;
  for (int i = tid; i < 4 * 1024; i += 256)
    al[i] = xc1[(size_t)(b0 + (i >> 10)) * 1024 + (i & 1023)];
  __syncthreads();
  float acc[4] = {};
  for (int i = 0; i < 1024; ++i) {
    float w = W[(size_t)i * 512 + j];
#pragma unroll
    for (int bb = 0; bb < 4; ++bb) acc[bb] += al[bb * 1024 + i] * w;
  }
  float bi = bias[j], sc = bn[j] * BNR, bt = bn[512 + j];
#pragma unroll
  for (int bb = 0; bb < 4; ++bb)
    out[(size_t)(b0 + bb) * 512 + j] = sc * fmaxf(0.f, acc[bb] + bi) + bt;
}

__global__ __launch_bounds__(256) void k_out(const float* __restrict__ xc2, const float* __restrict__ W,
                                             const float* __restrict__ ob, float* __restrict__ out) {
  __shared__ float red[4];
  int b = blockIdx.x, tid = threadIdx.x;
  float v = xc2[(size_t)b * 512 + tid] * W[tid] + xc2[(size_t)b * 512 + 256 + tid] * W[256 + tid];
  v = wave_red_sum(v);
  int wave = tid >> 6, lane = tid & 63;
  if (lane == 0) red[wave] = v;
  __syncthreads();
  if (tid == 0) out[b] = red[0] + red[1] + red[2] + red[3] + ob[0];
}

extern "C" void kernel_launch(void* const* d_in, const int* in_sizes, int n_in,
                              void* d_out, int out_size, void* d_ws, size_t ws_size,
                              hipStream_t stream) {
  (void)in_sizes; (void)n_in; (void)out_size; (void)ws_size;
  const float* x      = (const float*)d_in[0];
  const int*   eidx   = (const int*)d_in[1];
  const int*   src    = eidx;
  const int*   dst    = eidx + N_EDGES;
  const int*   target = (const int*)d_in[3];
  const float* W1 = (const float*)d_in[4];  const float* b1 = (const float*)d_in[5];
  const float* bn1 = (const float*)d_in[6]; const float* Wp1 = (const float*)d_in[7];
  const float* bp1 = (const float*)d_in[8];
  const float* W2 = (const float*)d_in[9];  const float* b2 = (const float*)d_in[10];
  const float* bn2 = (const float*)d_in[11]; const float* Wp2 = (const float*)d_in[12];
  const float* bp2 = (const float*)d_in[13];
  const float* W3 = (const float*)d_in[14]; const float* b3 = (const float*)d_in[15];
  const float* bn3 = (const float*)d_in[16]; const float* Wp3 = (const float*)d_in[17];
  const float* bp3 = (const float*)d_in[18];
  const float* fcg1_W = (const float*)d_in[19]; const float* fcg1_b = (const float*)d_in[20];
  const float* bn4 = (const float*)d_in[21];
  const float* emb = (const float*)d_in[22];
  const float* c1W = (const float*)d_in[23]; const float* c1b = (const float*)d_in[24];
  const float* bnx1 = (const float*)d_in[25];
  const float* c2W = (const float*)d_in[26]; const float* c2b = (const float*)d_in[27];
  const float* bnx2 = (const float*)d_in[28];
  const float* c3W = (const float*)d_in[29]; const float* c3b = (const float*)d_in[30];
  const float* bnx3 = (const float*)d_in[31];
  const float* fxt_W = (const float*)d_in[32]; const float* fxt_b = (const float*)d_in[33];
  const float* bn6 = (const float*)d_in[34];
  const float* fc1W = (const float*)d_in[35]; const float* fc1b = (const float*)d_in[36];
  const float* bn7 = (const float*)d_in[37];
  const float* fc2W = (const float*)d_in[38]; const float* fc2b = (const float*)d_in[39];
  const float* bn8 = (const float*)d_in[40];
  const float* outW = (const float*)d_in[41]; const float* outb = (const float*)d_in[42];

  char* ws = (char*)d_ws;
  size_t off = 0;
  auto alloc = [&](size_t bytes) -> void* {
    void* p = ws + off;
    off += (bytes + 255) & ~(size_t)255;
    return p;
  };
  float* dis   = (float*)alloc((size_t)N_NODES * 4);
  int*   cnt   = (int*)alloc((size_t)N_NODES * 4);
  int*   cursor= (int*)alloc((size_t)N_NODES * 4);
  int*   offs  = (int*)alloc((size_t)N_NODES * 4);
  int*   bsum  = (int*)alloc(1024);
  int*   csr   = (int*)alloc((size_t)N_EDGES * 4);
  float* cf    = (float*)alloc((size_t)N_EDGES * 4);
  float* h_a   = (float*)alloc((size_t)N_NODES * NF * 4);   // region; holds bf16 h rows (39 uints)
  float* h_b   = (float*)alloc((size_t)N_NODES * NF * 4);
  float* tbuf  = (float*)alloc((size_t)N_NODES * NF * 4);   // region; holds bf16 t
  float* gate  = (float*)alloc((size_t)N_NODES * 4);
  float* spre  = (float*)alloc((size_t)N_NODES * 4);
  float* xsum  = (float*)alloc(512 * 156 * 4);
  float* gbuf  = (float*)alloc(512 * 128 * 4);
  float* xt    = (float*)alloc(512 * 128 * 4);
  float* xc1   = (float*)alloc(512 * 1024 * 4);
  float* xc2   = (float*)alloc(512 * 512 * 4);
  unsigned short* tb = (unsigned short*)tbuf;
  unsigned* tu = (unsigned*)tbuf;
  unsigned* ha_u = (unsigned*)h_a;  unsigned short* ha_s = (unsigned short*)h_a;
  unsigned* hb_u = (unsigned*)h_b;  unsigned short* hb_s = (unsigned short*)h_b;
  // protein-branch aliases (GNN big buffers are dead by then)
  float* O1 = h_a;                      // 512*128*128 = 33.5 MB <= 40.9 MB
  float* O2 = h_b;                      // 512*64*128  = 16.8 MB
  float* Wt = tbuf;                     // 1000*384    = 1.54 MB
  float* P  = tbuf + 524288;            // +2 MB: 512*32*128 = 8.4 MB
  float* fxt_part = h_a;                // 8*512*128 = 2 MB (O1 dead after conv2)

  hipMemsetAsync(cnt, 0, (size_t)N_NODES * 4, stream);
  hipMemsetAsync(cursor, 0, (size_t)N_NODES * 4, stream);

  k_count<<<N_EDGES / 256, 256, 0, stream>>>(dst, cnt);
  k_dis<<<N_NODES / 256, 256, 0, stream>>>(cnt, dis);
  k_scan1<<<N_NODES / 512, 512, 0, stream>>>(cnt, offs, bsum);
  k_scan2<<<1, 256, 0, stream>>>(bsum);
  k_scan3<<<N_NODES / 512, 512, 0, stream>>>(offs, bsum);
  k_fill<<<N_EDGES / 256, 256, 0, stream>>>(src, dst, offs, cursor, dis, csr, cf);

  // layer 1
  k_gemm_f32<<<N_NODES / 64, 256, 0, stream>>>(x, W1, tb);
  k_agg<<<N_NODES / 4, 256, 0, stream>>>(tu, offs, cnt, csr, cf, dis, b1, bn1, Wp1, ha_u, spre);
  k_gate<<<N_NODES / 256, 256, 0, stream>>>(spre, offs, cnt, csr, cf, dis, bp1, gate);
  k_readout<<<NB, 128, 0, stream>>>(ha_s, gate, xsum, 0);
  // layer 2
  k_gemm_bf16<<<N_NODES / 64, 256, 0, stream>>>(ha_s, gate, W2, tb);
  k_agg<<<N_NODES / 4, 256, 0, stream>>>(tu, offs, cnt, csr, cf, dis, b2, bn2, Wp2, hb_u, spre);
  k_gate<<<N_NODES / 256, 256, 0, stream>>>(spre, offs, cnt, csr, cf, dis, bp2, gate);
  k_readout<<<NB, 128, 0, stream>>>(hb_s, gate, xsum, 1);
  // layer 3
  k_gemm_bf16<<<N_NODES / 64, 256, 0, stream>>>(hb_s, gate, W3, tb);
  k_agg<<<N_NODES / 4, 256, 0, stream>>>(tu, offs, cnt, csr, cf, dis, b3, bn3, Wp3, ha_u, spre);
  k_gate<<<N_NODES / 256, 256, 0, stream>>>(spre, offs, cnt, csr, cf, dis, bp3, gate);
  k_readout<<<NB, 128, 0, stream>>>(ha_s, gate, xsum, 1);

  k_fcg<<<NB, 128, 0, stream>>>(xsum, fcg1_W, fcg1_b, bn4, gbuf);

  // protein branch (reuses h_a/h_b/tbuf regions — all GNN reads complete above)
  k_transpose_w<<<1500, 256, 0, stream>>>(c1W, Wt);
  k_conv1<<<NB, 512, 0, stream>>>(Wt, target, emb, c1b, bnx1, O1);
  k_conv2<<<NB, 256, 0, stream>>>(O1, c2W, c2b, bnx2, O2);
  k_conv3<<<NB, 256, 0, stream>>>(O2, c3W, c3b, bnx3, P);
  // O1 (h_a) is dead after conv2 -> reuse for fxt partials
  k_fxt_part<<<512, 128, 0, stream>>>(P, fxt_W, fxt_part);
  k_fxt_red<<<256, 256, 0, stream>>>(fxt_part, fxt_b, bn6, xt);

  k_fc1<<<512, 256, 0, stream>>>(gbuf, xt, fc1W, fc1b, bn7, xc1);
  k_fc2<<<256, 256, 0, stream>>>(xc1, fc2W, fc2b, bn8, xc2);
  k_out<<<NB, 256, 0, stream>>>(xc2, outW, outb, (float*)d_out);
}

// Round 9
// 763.892 us; speedup vs baseline: 1.1702x; 1.1702x over previous
//
#include <hip/hip_runtime.h>
#include <hip/hip_bf16.h>
#include <cstddef>

#define N_NODES 131072
#define N_EDGES 1048576
#define NF 78
#define NB 512
#define BNR 0.9999950000374996f  // 1/sqrt(1+1e-5)

__device__ __forceinline__ float wave_red_sum(float v) {
  for (int off = 32; off > 0; off >>= 1) v += __shfl_down(v, off);
  return v;
}

__device__ __forceinline__ float bf2f(unsigned short u) {
  return __uint_as_float(((unsigned)u) << 16);
}

__device__ __forceinline__ unsigned f2bf_rn(float x) {  // round-to-nearest-even bf16 bits
  unsigned u = __float_as_uint(x);
  return (u + 0x7fffu + ((u >> 16) & 1u)) >> 16;
}

// ---------------- graph setup ----------------
__global__ void k_count(const int* __restrict__ dst, int* __restrict__ cnt) {
  int e = blockIdx.x * 256 + threadIdx.x;
  if (e < N_EDGES) atomicAdd(&cnt[dst[e]], 1);
}

__global__ void k_dis(const int* __restrict__ cnt, float* __restrict__ dis) {
  int n = blockIdx.x * 256 + threadIdx.x;
  if (n < N_NODES) dis[n] = rsqrtf(1.0f + (float)cnt[n]);
}

__global__ void k_scan1(const int* __restrict__ cnt, int* __restrict__ offs, int* __restrict__ bsum) {
  __shared__ int s[512];
  int gid = blockIdx.x * 512 + threadIdx.x;
  int v = cnt[gid];
  s[threadIdx.x] = v; __syncthreads();
  for (int off = 1; off < 512; off <<= 1) {
    int t = (threadIdx.x >= off) ? s[threadIdx.x - off] : 0;
    __syncthreads();
    s[threadIdx.x] += t;
    __syncthreads();
  }
  offs[gid] = s[threadIdx.x] - v;               // exclusive
  if (threadIdx.x == 511) bsum[blockIdx.x] = s[511];
}

__global__ void k_scan2(int* __restrict__ bsum) {  // 1 block, 256 threads
  __shared__ int s[256];
  int v = bsum[threadIdx.x];
  s[threadIdx.x] = v; __syncthreads();
  for (int off = 1; off < 256; off <<= 1) {
    int t = (threadIdx.x >= off) ? s[threadIdx.x - off] : 0;
    __syncthreads();
    s[threadIdx.x] += t;
    __syncthreads();
  }
  bsum[threadIdx.x] = s[threadIdx.x] - v;       // exclusive
}

__global__ void k_scan3(int* __restrict__ offs, const int* __restrict__ bsum) {
  int gid = blockIdx.x * 512 + threadIdx.x;
  offs[gid] += bsum[blockIdx.x];
}

__global__ void k_fill(const int* __restrict__ src, const int* __restrict__ dst,
                       const int* __restrict__ offs, int* __restrict__ cursor,
                       const float* __restrict__ dis, int* __restrict__ csr,
                       float* __restrict__ cf) {
  int e = blockIdx.x * 256 + threadIdx.x;
  if (e < N_EDGES) {
    int s = src[e], d = dst[e];
    int pos = offs[d] + atomicAdd(&cursor[d], 1);
    csr[pos] = s;
    cf[pos] = dis[s] * dis[d];
  }
}

// ---------------- GCN layer ----------------
// t = h @ W  (layer 1, f32 input, no gate), output bf16
__global__ __launch_bounds__(256) void k_gemm_f32(const float* __restrict__ h,
                                                  const float* __restrict__ W,
                                                  unsigned short* __restrict__ t) {
  __shared__ float hs[64 * NF];
  __shared__ float Ws[NF * NF];
  int n0 = blockIdx.x * 64;
  int tid = threadIdx.x;
  for (int i = tid; i < NF * NF; i += 256) Ws[i] = W[i];
  for (int i = tid; i < 64 * NF; i += 256) hs[i] = h[(size_t)n0 * NF + i];
  __syncthreads();
  int rg = tid >> 4, cg = tid & 15;
  int r0 = rg * 4, c0 = cg * 5;
  float acc[4][5] = {};
  for (int k = 0; k < NF; ++k) {
    float wv[5];
#pragma unroll
    for (int j = 0; j < 5; ++j) wv[j] = (c0 + j < NF) ? Ws[k * NF + c0 + j] : 0.f;
#pragma unroll
    for (int i = 0; i < 4; ++i) {
      float hv = hs[(r0 + i) * NF + k];
#pragma unroll
      for (int j = 0; j < 5; ++j) acc[i][j] += hv * wv[j];
    }
  }
  for (int i = 0; i < 4; ++i)
    for (int j = 0; j < 5; ++j) {
      int c = c0 + j;
      if (c < NF) t[(size_t)(n0 + r0 + i) * NF + c] = (unsigned short)f2bf_rn(acc[i][j]);
    }
}

// t = (h .* gate) @ W  (layers 2,3; h bf16), output bf16
__global__ __launch_bounds__(256) void k_gemm_bf16(const unsigned short* __restrict__ h,
                                                   const float* __restrict__ gate,
                                                   const float* __restrict__ W,
                                                   unsigned short* __restrict__ t) {
  __shared__ float hs[64 * NF];
  __shared__ float Ws[NF * NF];
  int n0 = blockIdx.x * 64;
  int tid = threadIdx.x;
  for (int i = tid; i < NF * NF; i += 256) Ws[i] = W[i];
  for (int i = tid; i < 64 * NF; i += 256) {
    int r = i / NF;
    hs[i] = bf2f(h[(size_t)n0 * NF + i]) * gate[n0 + r];
  }
  __syncthreads();
  int rg = tid >> 4, cg = tid & 15;
  int r0 = rg * 4, c0 = cg * 5;
  float acc[4][5] = {};
  for (int k = 0; k < NF; ++k) {
    float wv[5];
#pragma unroll
    for (int j = 0; j < 5; ++j) wv[j] = (c0 + j < NF) ? Ws[k * NF + c0 + j] : 0.f;
#pragma unroll
    for (int i = 0; i < 4; ++i) {
      float hv = hs[(r0 + i) * NF + k];
#pragma unroll
      for (int j = 0; j < 5; ++j) acc[i][j] += hv * wv[j];
    }
  }
  for (int i = 0; i < 4; ++i)
    for (int j = 0; j < 5; ++j) {
      int c = c0 + j;
      if (c < NF) t[(size_t)(n0 + r0 + i) * NF + c] = (unsigned short)f2bf_rn(acc[i][j]);
    }
}

// out = relu(bn(agg + t*selfc + b)); also spre = out . Wp  (one wave per node)
// Row = 39 uints (78 bf16). One global_load_dword per edge; lanes 39-63 clamp.
__global__ __launch_bounds__(256) void k_agg(const unsigned* __restrict__ tu, const int* __restrict__ offs,
                                             const int* __restrict__ cnt, const int* __restrict__ csr,
                                             const float* __restrict__ cf, const float* __restrict__ dis,
                                             const float* __restrict__ bias, const float* __restrict__ bn,
                                             const float* __restrict__ Wp,
                                             unsigned* __restrict__ hout, float* __restrict__ spre) {
  int wave = threadIdx.x >> 6, lane = threadIdx.x & 63;
  int n = blockIdx.x * 4 + wave;
  float disn = dis[n];
  int st = offs[n], cn = cnt[n];
  int cn1 = cn < 64 ? cn : 64;
  int sIdx = 0; float sCoef = 0.f;
  if (lane < cn1) {
    sIdx = csr[st + lane] * 39;
    sCoef = cf[st + lane];
  }
  int lc = lane < 39 ? lane : 38;
  int rowu = n * 39;
  float selfc = disn * disn;
  unsigned su = tu[rowu + lc];
  float a0e = __uint_as_float(su << 16) * selfc;
  float a1e = __uint_as_float(su & 0xffff0000u) * selfc;
  float a0o = 0.f, a1o = 0.f;
  int j = 0;
#pragma unroll 4
  for (; j + 2 <= cn1; j += 2) {
    int sb0 = __shfl(sIdx, j);     float c0 = __shfl(sCoef, j);
    int sb1 = __shfl(sIdx, j + 1); float c1 = __shfl(sCoef, j + 1);
    unsigned u0 = tu[sb0 + lc];
    unsigned u1 = tu[sb1 + lc];
    a0e += c0 * __uint_as_float(u0 << 16);
    a1e += c0 * __uint_as_float(u0 & 0xffff0000u);
    a0o += c1 * __uint_as_float(u1 << 16);
    a1o += c1 * __uint_as_float(u1 & 0xffff0000u);
  }
  if (j < cn1) {
    int sb = __shfl(sIdx, j); float c = __shfl(sCoef, j);
    unsigned u = tu[sb + lc];
    a0e += c * __uint_as_float(u << 16);
    a1e += c * __uint_as_float(u & 0xffff0000u);
  }
  for (j = 64; j < cn; ++j) {  // safety tail, effectively never taken
    int sb = csr[st + j] * 39; float c = cf[st + j];
    unsigned u = tu[sb + lc];
    a0e += c * __uint_as_float(u << 16);
    a1e += c * __uint_as_float(u & 0xffff0000u);
  }
  float a0 = a0e + a0o, a1 = a1e + a1o;
  float h0 = 0.f, h1 = 0.f;
  float2 wp = make_float2(0.f, 0.f);
  if (lane < 39) {
    float2 bi = *reinterpret_cast<const float2*>(bias + 2 * lane);
    float2 gm = *reinterpret_cast<const float2*>(bn + 2 * lane);
    float2 bt = *reinterpret_cast<const float2*>(bn + NF + 2 * lane);
    h0 = fmaxf(0.f, gm.x * BNR * (a0 + bi.x) + bt.x);
    h1 = fmaxf(0.f, gm.y * BNR * (a1 + bi.y) + bt.y);
    hout[rowu + lane] = f2bf_rn(h0) | (f2bf_rn(h1) << 16);
    wp = *reinterpret_cast<const float2*>(Wp + 2 * lane);
  }
  float p = h0 * wp.x + h1 * wp.y;
  p = wave_red_sum(p);
  if (lane == 0) spre[n] = p;
}

__global__ void k_gate(const float* __restrict__ spre, const int* __restrict__ offs,
                       const int* __restrict__ cnt, const int* __restrict__ csr,
                       const float* __restrict__ cf, const float* __restrict__ dis,
                       const float* __restrict__ bp, float* __restrict__ gate) {
  int n = blockIdx.x * 256 + threadIdx.x;
  if (n >= N_NODES) return;
  float disn = dis[n];
  float s = bp[0] + disn * disn * spre[n];
  int st = offs[n], cn = cnt[n];
#pragma unroll 4
  for (int j = 0; j < cn; ++j) {
    s += cf[st + j] * spre[csr[st + j]];
  }
  gate[n] = tanhf(s);
}

// per-graph max & mean over contiguous 256-node segments; accumulate x1+x2+x3
__global__ __launch_bounds__(128) void k_readout(const unsigned short* __restrict__ h,
                                                 const float* __restrict__ gate,
                                                 float* __restrict__ xsum, int accum) {
  __shared__ float gl[256];
  int b = blockIdx.x, tid = threadIdx.x;
  for (int i = tid; i < 256; i += 128) gl[i] = gate[b * 256 + i];
  __syncthreads();
  if (tid >= NF) return;
  float mx = -1e30f, sm = 0.f;
  const unsigned short* hp = h + (size_t)b * 256 * NF + tid;
  for (int nn = 0; nn < 256; ++nn) {
    float v = bf2f(hp[(size_t)nn * NF]) * gl[nn];
    mx = fmaxf(mx, v);
    sm += v;
  }
  float mean = sm * (1.f / 256.f);
  if (accum) {
    xsum[b * 156 + tid] += mx;
    xsum[b * 156 + NF + tid] += mean;
  } else {
    xsum[b * 156 + tid] = mx;
    xsum[b * 156 + NF + tid] = mean;
  }
}

// g = relu(bn4((x1+x2+x3) @ fcg1_W + fcg1_b))
__global__ __launch_bounds__(128) void k_fcg(const float* __restrict__ xsum, const float* __restrict__ W,
                                             const float* __restrict__ bias, const float* __restrict__ bn,
                                             float* __restrict__ g) {
  __shared__ float xs[156];
  int b = blockIdx.x, tid = threadIdx.x;
  for (int i = tid; i < 156; i += 128) xs[i] = xsum[b * 156 + i];
  __syncthreads();
  float acc = bias[tid];
  for (int i = 0; i < 156; ++i) acc += xs[i] * W[i * 128 + tid];
  g[b * 128 + tid] = fmaxf(0.f, bn[tid] * BNR * acc + bn[128 + tid]);
}

// ---------------- protein branch ----------------
// Wt[i*384 + oc*3 + k] = c1W[oc*3000 + i*3 + k]
__global__ void k_transpose_w(const float* __restrict__ c1W, float* __restrict__ Wt) {
  int idx = blockIdx.x * 256 + threadIdx.x;
  if (idx >= 384000) return;
  int i = idx / 384;
  int r = idx - i * 384;
  int oc = r / 3, k = r - oc * 3;
  Wt[idx] = c1W[oc * 3000 + i * 3 + k];
}

// conv1 via vocab bucketing.
// 2a: counting-sort positions by vocab (INT LDS atomics, native); border sorted by v.
// 2b: outer loop over buckets (flushes OUTSIDE inner loop, no branches inside);
//     inner loop unroll-4 dual-acc -> ~8 independent ds_read+global_load in flight.
// 3:  el padded to stride 132; 9x ds_read_b128 broadcast per v.
__global__ __launch_bounds__(512) void k_conv1(const float* __restrict__ Wt, const int* __restrict__ target,
                                               const float* __restrict__ emb, const float* __restrict__ c1b,
                                               const float* __restrict__ bnx, float* __restrict__ O) {
  __shared__ float G[26 * 384];
  __shared__ float el[26 * 132];
  __shared__ int tg[1000];
  __shared__ int border[1000];
  __shared__ int cnt26[26], boff[27], cur26[26];
  int b = blockIdx.x, tid = threadIdx.x;
  if (tid < 26) cnt26[tid] = 0;
  for (int i = tid; i < 26 * 132; i += 512) {
    int v = i / 132, hp = i - v * 132;
    el[i] = (hp >= 1 && hp <= 128) ? emb[v * 128 + hp - 1] : 0.f;
  }
  for (int i = tid; i < 1000; i += 512) tg[i] = target[b * 1000 + i];
  __syncthreads();
  for (int i = tid; i < 1000; i += 512) atomicAdd(&cnt26[tg[i]], 1);
  __syncthreads();
  if (tid == 0) {
    int run = 0;
    for (int v = 0; v < 26; ++v) { boff[v] = run; cur26[v] = run; run += cnt26[v]; }
    boff[26] = run;
  }
  __syncthreads();
  for (int i = tid; i < 1000; i += 512) {
    int v = tg[i];
    int slot = atomicAdd(&cur26[v], 1);
    border[slot] = i;
  }
  __syncthreads();
  if (tid < 384) {
    for (int v = 0; v < 26; ++v) {
      int k0 = boff[v], k1 = boff[v + 1];
      float ae = 0.f, ao = 0.f;
      int k = k0;
#pragma unroll 4
      for (; k + 2 <= k1; k += 2) {
        int p0 = border[k];
        int p1 = border[k + 1];
        ae += Wt[(size_t)p0 * 384 + tid];
        ao += Wt[(size_t)p1 * 384 + tid];
      }
      if (k < k1) ae += Wt[(size_t)border[k] * 384 + tid];
      G[v * 384 + tid] = ae + ao;
    }
  }
  __syncthreads();
  int oc = tid & 127, q = tid >> 7;
  int h0 = q * 32;
  float acc[32];
#pragma unroll
  for (int j = 0; j < 32; ++j) acc[j] = 0.f;
  for (int v = 0; v < 26; ++v) {
    float g0 = G[v * 384 + oc * 3 + 0];
    float g1 = G[v * 384 + oc * 3 + 1];
    float g2 = G[v * 384 + oc * 3 + 2];
    float4 buf[9];
    const float4* ep = reinterpret_cast<const float4*>(&el[v * 132 + h0]);
#pragma unroll
    for (int r = 0; r < 9; ++r) buf[r] = ep[r];
    const float* bf = reinterpret_cast<const float*>(buf);
#pragma unroll
    for (int j = 0; j < 32; ++j)
      acc[j] += g0 * bf[j] + g1 * bf[j + 1] + g2 * bf[j + 2];
  }
  float bia = c1b[oc];
  float sc = bnx[oc] * BNR, bt = bnx[128 + oc];
  float* outp = O + (size_t)b * 16384 + oc * 128 + h0;
#pragma unroll
  for (int j = 0; j < 32; ++j) acc[j] = fmaxf(0.f, sc * (acc[j] + bia) + bt);
#pragma unroll
  for (int j = 0; j < 8; ++j)
    *reinterpret_cast<float4*>(outp + 4 * j) =
        make_float4(acc[4 * j], acc[4 * j + 1], acc[4 * j + 2], acc[4 * j + 3]);
}

__global__ __launch_bounds__(256) void k_conv2(const float* __restrict__ X, const float* __restrict__ W,
                                               const float* __restrict__ bias, const float* __restrict__ bnx,
                                               float* __restrict__ O) {
  __shared__ float xl[128 * 136];
  int b = blockIdx.x, tid = threadIdx.x;
  for (int i = tid; i < 128 * 32; i += 256) {
    int row = i >> 5, c4 = (i & 31) * 4;
    float4 v = *reinterpret_cast<const float4*>(X + (size_t)b * 16384 + row * 128 + c4);
    *reinterpret_cast<float4*>(&xl[row * 136 + 4 + c4]) = v;
  }
  if (tid < 128) { xl[tid * 136 + 3] = 0.f; xl[tid * 136 + 132] = 0.f; }
  __syncthreads();
  int oc = tid & 63, q = tid >> 6;
  int h0 = q * 32;
  float acc[32];
#pragma unroll
  for (int j = 0; j < 32; ++j) acc[j] = 0.f;
  const float* wp = W + oc * 384;
  for (int i = 0; i < 128; ++i) {
    float w0 = wp[i * 3], w1 = wp[i * 3 + 1], w2 = wp[i * 3 + 2];
    const float* xr = &xl[i * 136 + 3 + h0];
    float e0 = xr[0], e1 = xr[1];
#pragma unroll
    for (int j = 0; j < 32; ++j) {
      float e2 = xr[j + 2];
      acc[j] += w0 * e0 + w1 * e1 + w2 * e2;
      e0 = e1; e1 = e2;
    }
  }
  float bia = bias[oc], sc = bnx[oc] * BNR, bt = bnx[64 + oc];
  float* outp = O + (size_t)b * 8192 + oc * 128 + h0;
#pragma unroll
  for (int j = 0; j < 32; ++j) acc[j] = fmaxf(0.f, sc * (acc[j] + bia) + bt);
#pragma unroll
  for (int j = 0; j < 8; ++j)
    *reinterpret_cast<float4*>(outp + 4 * j) =
        make_float4(acc[4 * j], acc[4 * j + 1], acc[4 * j + 2], acc[4 * j + 3]);
}

__global__ __launch_bounds__(256) void k_conv3(const float* __restrict__ X, const float* __restrict__ W,
                                               const float* __restrict__ bias, const float* __restrict__ bnx,
                                               float* __restrict__ O) {
  __shared__ float xl[64 * 136];
  int b = blockIdx.x, tid = threadIdx.x;
  for (int i = tid; i < 64 * 32; i += 256) {
    int row = i >> 5, c4 = (i & 31) * 4;
    float4 v = *reinterpret_cast<const float4*>(X + (size_t)b * 8192 + row * 128 + c4);
    *reinterpret_cast<float4*>(&xl[row * 136 + 4 + c4]) = v;
  }
  if (tid < 64) { xl[tid * 136 + 3] = 0.f; xl[tid * 136 + 132] = 0.f; }
  __syncthreads();
  int oc = tid & 31, q = tid >> 5;  // 0..7
  int h0 = q * 16;
  float acc[16];
#pragma unroll
  for (int j = 0; j < 16; ++j) acc[j] = 0.f;
  const float* wp = W + oc * 192;
  for (int i = 0; i < 64; ++i) {
    float w0 = wp[i * 3], w1 = wp[i * 3 + 1], w2 = wp[i * 3 + 2];
    const float* xr = &xl[i * 136 + 3 + h0];
    float e0 = xr[0], e1 = xr[1];
#pragma unroll
    for (int j = 0; j < 16; ++j) {
      float e2 = xr[j + 2];
      acc[j] += w0 * e0 + w1 * e1 + w2 * e2;
      e0 = e1; e1 = e2;
    }
  }
  float bia = bias[oc], sc = bnx[oc] * BNR, bt = bnx[32 + oc];
  float* outp = O + (size_t)b * 4096 + oc * 128 + h0;
#pragma unroll
  for (int j = 0; j < 16; ++j) acc[j] = fmaxf(0.f, sc * (acc[j] + bia) + bt);
#pragma unroll
  for (int j = 0; j < 4; ++j)
    *reinterpret_cast<float4*>(outp + 4 * j) =
        make_float4(acc[4 * j], acc[4 * j + 1], acc[4 * j + 2], acc[4 * j + 3]);
}

// ---- fxt: [512,4096] @ [4096,128], K-split 8 ways for parallelism ----
__global__ __launch_bounds__(128) void k_fxt_part(const float* __restrict__ P, const float* __restrict__ W,
                                                  float* __restrict__ part) {
  __shared__ float pl[8 * 512];
  int bblk = blockIdx.x >> 3, kc = blockIdx.x & 7;
  int b0 = bblk * 8, tid = threadIdx.x;
  for (int i = tid; i < 8 * 512; i += 128) {
    int bb = i >> 9, k = i & 511;
    pl[i] = P[(size_t)(b0 + bb) * 4096 + kc * 512 + k];
  }
  __syncthreads();
  float acc[8] = {};
  const float* wp = W + (size_t)kc * 512 * 128 + tid;
  for (int k = 0; k < 512; ++k) {
    float w = wp[(size_t)k * 128];
#pragma unroll
    for (int bb = 0; bb < 8; ++bb) acc[bb] += pl[bb * 512 + k] * w;
  }
#pragma unroll
  for (int bb = 0; bb < 8; ++bb)
    part[((size_t)kc * 512 + b0 + bb) * 128 + tid] = acc[bb];
}

// xt = bn6(relu(sum_kc part + fxt_b))   (bn AFTER relu)
__global__ __launch_bounds__(256) void k_fxt_red(const float* __restrict__ part, const float* __restrict__ bias,
                                                 const float* __restrict__ bn, float* __restrict__ xt) {
  int idx = blockIdx.x * 256 + threadIdx.x;  // 512*128
  int j = idx & 127;
  float s = 0.f;
#pragma unroll
  for (int kc = 0; kc < 8; ++kc) s += part[(size_t)kc * 65536 + idx];
  xt[idx] = bn[j] * BNR * fmaxf(0.f, s + bias[j]) + bn[128 + j];
}

// xc1 = bn7(relu([g|xt] @ fc1W + fc1b)); grid 512 = (bblk 0..127)x(jb 0..3)
__global__ __launch_bounds__(256) void k_fc1(const float* __restrict__ g, const float* __restrict__ xt,
                                             const float* __restrict__ W, const float* __restrict__ bias,
                                             const float* __restrict__ bn, float* __restrict__ out) {
  __shared__ float al[4 * 256];
  int bblk = blockIdx.x >> 2, jb = blockIdx.x & 3;
  int b0 = bblk * 4, tid = threadIdx.x;
  int j = jb * 256 + tid;
  for (int i = tid; i < 4 * 256; i += 256) {
    int bb = i >> 8, c = i & 255;
    al[i] = (c < 128) ? g[(b0 + bb) * 128 + c] : xt[(b0 + bb) * 128 + c - 128];
  }
  __syncthreads();
  float acc[4] = {};
  for (int i = 0; i < 256; ++i) {
    float w = W[(size_t)i * 1024 + j];
#pragma unroll
    for (int bb = 0; bb < 4; ++bb) acc[bb] += al[bb * 256 + i] * w;
  }
  float bi = bias[j], sc = bn[j] * BNR, bt = bn[1024 + j];
#pragma unroll
  for (int bb = 0; bb < 4; ++bb)
    out[(size_t)(b0 + bb) * 1024 + j] = sc * fmaxf(0.f, acc[bb] + bi) + bt;
}

// xc2 = bn8(relu(xc1 @ fc2W + fc2b)); grid 256 = (bblk 0..127)x(jb 0..1)
__global__ __launch_bounds__(256) void k_fc2(const float* __restrict__ xc1, const float* __restrict__ W,
                                             const float* __restrict__ bias, const float* __restrict__ bn,
                                             float* __restrict__ out) {
  __shared__ float al[4 * 1024];
  int bblk = blockIdx.x >> 1, jb = blockIdx.x & 1;
  int b0 = bblk * 4, tid = threadIdx.x;
  int j = jb * 256 + tid;
  for (int i = tid; i < 4 * 1024; i += 256)
    al[i] = xc1[(size_t)(b0 + (i >> 10)) * 1024 + (i & 1023)];
  __syncthreads();
  float acc[4] = {};
  for (int i = 0; i < 1024; ++i) {
    float w = W[(size_t)i * 512 + j];
#pragma unroll
    for (int bb = 0; bb < 4; ++bb) acc[bb] += al[bb * 1024 + i] * w;
  }
  float bi = bias[j], sc = bn[j] * BNR, bt = bn[512 + j];
#pragma unroll
  for (int bb = 0; bb < 4; ++bb)
    out[(size_t)(b0 + bb) * 512 + j] = sc * fmaxf(0.f, acc[bb] + bi) + bt;
}

__global__ __launch_bounds__(256) void k_out(const float* __restrict__ xc2, const float* __restrict__ W,
                                             const float* __restrict__ ob, float* __restrict__ out) {
  __shared__ float red[4];
  int b = blockIdx.x, tid = threadIdx.x;
  float v = xc2[(size_t)b * 512 + tid] * W[tid] + xc2[(size_t)b * 512 + 256 + tid] * W[256 + tid];
  v = wave_red_sum(v);
  int wave = tid >> 6, lane = tid & 63;
  if (lane == 0) red[wave] = v;
  __syncthreads();
  if (tid == 0) out[b] = red[0] + red[1] + red[2] + red[3] + ob[0];
}

extern "C" void kernel_launch(void* const* d_in, const int* in_sizes, int n_in,
                              void* d_out, int out_size, void* d_ws, size_t ws_size,
                              hipStream_t stream) {
  (void)in_sizes; (void)n_in; (void)out_size; (void)ws_size;
  const float* x      = (const float*)d_in[0];
  const int*   eidx   = (const int*)d_in[1];
  const int*   src    = eidx;
  const int*   dst    = eidx + N_EDGES;
  const int*   target = (const int*)d_in[3];
  const float* W1 = (const float*)d_in[4];  const float* b1 = (const float*)d_in[5];
  const float* bn1 = (const float*)d_in[6]; const float* Wp1 = (const float*)d_in[7];
  const float* bp1 = (const float*)d_in[8];
  const float* W2 = (const float*)d_in[9];  const float* b2 = (const float*)d_in[10];
  const float* bn2 = (const float*)d_in[11]; const float* Wp2 = (const float*)d_in[12];
  const float* bp2 = (const float*)d_in[13];
  const float* W3 = (const float*)d_in[14]; const float* b3 = (const float*)d_in[15];
  const float* bn3 = (const float*)d_in[16]; const float* Wp3 = (const float*)d_in[17];
  const float* bp3 = (const float*)d_in[18];
  const float* fcg1_W = (const float*)d_in[19]; const float* fcg1_b = (const float*)d_in[20];
  const float* bn4 = (const float*)d_in[21];
  const float* emb = (const float*)d_in[22];
  const float* c1W = (const float*)d_in[23]; const float* c1b = (const float*)d_in[24];
  const float* bnx1 = (const float*)d_in[25];
  const float* c2W = (const float*)d_in[26]; const float* c2b = (const float*)d_in[27];
  const float* bnx2 = (const float*)d_in[28];
  const float* c3W = (const float*)d_in[29]; const float* c3b = (const float*)d_in[30];
  const float* bnx3 = (const float*)d_in[31];
  const float* fxt_W = (const float*)d_in[32]; const float* fxt_b = (const float*)d_in[33];
  const float* bn6 = (const float*)d_in[34];
  const float* fc1W = (const float*)d_in[35]; const float* fc1b = (const float*)d_in[36];
  const float* bn7 = (const float*)d_in[37];
  const float* fc2W = (const float*)d_in[38]; const float* fc2b = (const float*)d_in[39];
  const float* bn8 = (const float*)d_in[40];
  const float* outW = (const float*)d_in[41]; const float* outb = (const float*)d_in[42];

  char* ws = (char*)d_ws;
  size_t off = 0;
  auto alloc = [&](size_t bytes) -> void* {
    void* p = ws + off;
    off += (bytes + 255) & ~(size_t)255;
    return p;
  };
  float* dis   = (float*)alloc((size_t)N_NODES * 4);
  int*   cnt   = (int*)alloc((size_t)N_NODES * 4);
  int*   cursor= (int*)alloc((size_t)N_NODES * 4);
  int*   offs  = (int*)alloc((size_t)N_NODES * 4);
  int*   bsum  = (int*)alloc(1024);
  int*   csr   = (int*)alloc((size_t)N_EDGES * 4);
  float* cf    = (float*)alloc((size_t)N_EDGES * 4);
  float* h_a   = (float*)alloc((size_t)N_NODES * NF * 4);   // region; holds bf16 h rows (39 uints)
  float* h_b   = (float*)alloc((size_t)N_NODES * NF * 4);
  float* tbuf  = (float*)alloc((size_t)N_NODES * NF * 4);   // region; holds bf16 t
  float* gate  = (float*)alloc((size_t)N_NODES * 4);
  float* spre  = (float*)alloc((size_t)N_NODES * 4);
  float* xsum  = (float*)alloc(512 * 156 * 4);
  float* gbuf  = (float*)alloc(512 * 128 * 4);
  float* xt    = (float*)alloc(512 * 128 * 4);
  float* xc1   = (float*)alloc(512 * 1024 * 4);
  float* xc2   = (float*)alloc(512 * 512 * 4);
  unsigned short* tb = (unsigned short*)tbuf;
  unsigned* tu = (unsigned*)tbuf;
  unsigned* ha_u = (unsigned*)h_a;  unsigned short* ha_s = (unsigned short*)h_a;
  unsigned* hb_u = (unsigned*)h_b;  unsigned short* hb_s = (unsigned short*)h_b;
  // protein-branch aliases (GNN big buffers are dead by then)
  float* O1 = h_a;                      // 512*128*128 = 33.5 MB <= 40.9 MB
  float* O2 = h_b;                      // 512*64*128  = 16.8 MB
  float* Wt = tbuf;                     // 1000*384    = 1.54 MB
  float* P  = tbuf + 524288;            // +2 MB: 512*32*128 = 8.4 MB
  float* fxt_part = h_a;                // 8*512*128 = 2 MB (O1 dead after conv2)

  hipMemsetAsync(cnt, 0, (size_t)N_NODES * 4, stream);
  hipMemsetAsync(cursor, 0, (size_t)N_NODES * 4, stream);

  k_count<<<N_EDGES / 256, 256, 0, stream>>>(dst, cnt);
  k_dis<<<N_NODES / 256, 256, 0, stream>>>(cnt, dis);
  k_scan1<<<N_NODES / 512, 512, 0, stream>>>(cnt, offs, bsum);
  k_scan2<<<1, 256, 0, stream>>>(bsum);
  k_scan3<<<N_NODES / 512, 512, 0, stream>>>(offs, bsum);
  k_fill<<<N_EDGES / 256, 256, 0, stream>>>(src, dst, offs, cursor, dis, csr, cf);

  // layer 1
  k_gemm_f32<<<N_NODES / 64, 256, 0, stream>>>(x, W1, tb);
  k_agg<<<N_NODES / 4, 256, 0, stream>>>(tu, offs, cnt, csr, cf, dis, b1, bn1, Wp1, ha_u, spre);
  k_gate<<<N_NODES / 256, 256, 0, stream>>>(spre, offs, cnt, csr, cf, dis, bp1, gate);
  k_readout<<<NB, 128, 0, stream>>>(ha_s, gate, xsum, 0);
  // layer 2
  k_gemm_bf16<<<N_NODES / 64, 256, 0, stream>>>(ha_s, gate, W2, tb);
  k_agg<<<N_NODES / 4, 256, 0, stream>>>(tu, offs, cnt, csr, cf, dis, b2, bn2, Wp2, hb_u, spre);
  k_gate<<<N_NODES / 256, 256, 0, stream>>>(spre, offs, cnt, csr, cf, dis, bp2, gate);
  k_readout<<<NB, 128, 0, stream>>>(hb_s, gate, xsum, 1);
  // layer 3
  k_gemm_bf16<<<N_NODES / 64, 256, 0, stream>>>(hb_s, gate, W3, tb);
  k_agg<<<N_NODES / 4, 256, 0, stream>>>(tu, offs, cnt, csr, cf, dis, b3, bn3, Wp3, ha_u, spre);
  k_gate<<<N_NODES / 256, 256, 0, stream>>>(spre, offs, cnt, csr, cf, dis, bp3, gate);
  k_readout<<<NB, 128, 0, stream>>>(ha_s, gate, xsum, 1);

  k_fcg<<<NB, 128, 0, stream>>>(xsum, fcg1_W, fcg1_b, bn4, gbuf);

  // protein branch (reuses h_a/h_b/tbuf regions — all GNN reads complete above)
  k_transpose_w<<<1500, 256, 0, stream>>>(c1W, Wt);
  k_conv1<<<NB, 512, 0, stream>>>(Wt, target, emb, c1b, bnx1, O1);
  k_conv2<<<NB, 256, 0, stream>>>(O1, c2W, c2b, bnx2, O2);
  k_conv3<<<NB, 256, 0, stream>>>(O2, c3W, c3b, bnx3, P);
  // O1 (h_a) is dead after conv2 -> reuse for fxt partials
  k_fxt_part<<<512, 128, 0, stream>>>(P, fxt_W, fxt_part);
  k_fxt_red<<<256, 256, 0, stream>>>(fxt_part, fxt_b, bn6, xt);

  k_fc1<<<512, 256, 0, stream>>>(gbuf, xt, fc1W, fc1b, bn7, xc1);
  k_fc2<<<256, 256, 0, stream>>>(xc1, fc2W, fc2b, bn8, xc2);
  k_out<<<NB, 256, 0, stream>>>(xc2, outW, outb, (float*)d_out);
}

// Round 10
// 761.027 us; speedup vs baseline: 1.1746x; 1.0038x over previous
//
#include <hip/hip_runtime.h>
#include <hip/hip_bf16.h>
#include <cstddef>

#define N_NODES 131072
#define N_EDGES 1048576
#define NF 78
#define NB 512
#define BNR 0.9999950000374996f  // 1/sqrt(1+1e-5)

__device__ __forceinline__ float wave_red_sum(float v) {
  for (int off = 32; off > 0; off >>= 1) v += __shfl_down(v, off);
  return v;
}

__device__ __forceinline__ float bf2f(unsigned short u) {
  return __uint_as_float(((unsigned)u) << 16);
}

__device__ __forceinline__ unsigned f2bf_rn(float x) {  // round-to-nearest-even bf16 bits
  unsigned u = __float_as_uint(x);
  return (u + 0x7fffu + ((u >> 16) & 1u)) >> 16;
}

// ---------------- graph setup ----------------
__global__ void k_count(const int* __restrict__ dst, int* __restrict__ cnt) {
  int e = blockIdx.x * 256 + threadIdx.x;
  if (e < N_EDGES) atomicAdd(&cnt[dst[e]], 1);
}

__global__ void k_dis(const int* __restrict__ cnt, float* __restrict__ dis) {
  int n = blockIdx.x * 256 + threadIdx.x;
  if (n < N_NODES) dis[n] = rsqrtf(1.0f + (float)cnt[n]);
}

__global__ void k_scan1(const int* __restrict__ cnt, int* __restrict__ offs, int* __restrict__ bsum) {
  __shared__ int s[512];
  int gid = blockIdx.x * 512 + threadIdx.x;
  int v = cnt[gid];
  s[threadIdx.x] = v; __syncthreads();
  for (int off = 1; off < 512; off <<= 1) {
    int t = (threadIdx.x >= off) ? s[threadIdx.x - off] : 0;
    __syncthreads();
    s[threadIdx.x] += t;
    __syncthreads();
  }
  offs[gid] = s[threadIdx.x] - v;               // exclusive
  if (threadIdx.x == 511) bsum[blockIdx.x] = s[511];
}

__global__ void k_scan2(int* __restrict__ bsum) {  // 1 block, 256 threads
  __shared__ int s[256];
  int v = bsum[threadIdx.x];
  s[threadIdx.x] = v; __syncthreads();
  for (int off = 1; off < 256; off <<= 1) {
    int t = (threadIdx.x >= off) ? s[threadIdx.x - off] : 0;
    __syncthreads();
    s[threadIdx.x] += t;
    __syncthreads();
  }
  bsum[threadIdx.x] = s[threadIdx.x] - v;       // exclusive
}

__global__ void k_scan3(int* __restrict__ offs, const int* __restrict__ bsum) {
  int gid = blockIdx.x * 512 + threadIdx.x;
  offs[gid] += bsum[blockIdx.x];
}

__global__ void k_fill(const int* __restrict__ src, const int* __restrict__ dst,
                       const int* __restrict__ offs, int* __restrict__ cursor,
                       const float* __restrict__ dis, int* __restrict__ csr,
                       float* __restrict__ cf) {
  int e = blockIdx.x * 256 + threadIdx.x;
  if (e < N_EDGES) {
    int s = src[e], d = dst[e];
    int pos = offs[d] + atomicAdd(&cursor[d], 1);
    csr[pos] = s;
    cf[pos] = dis[s] * dis[d];
  }
}

// ---------------- GCN layer ----------------
// t = h @ W  (layer 1, f32 input, no gate), output bf16
__global__ __launch_bounds__(256) void k_gemm_f32(const float* __restrict__ h,
                                                  const float* __restrict__ W,
                                                  unsigned short* __restrict__ t) {
  __shared__ float hs[64 * NF];
  __shared__ float Ws[NF * NF];
  int n0 = blockIdx.x * 64;
  int tid = threadIdx.x;
  for (int i = tid; i < NF * NF; i += 256) Ws[i] = W[i];
  for (int i = tid; i < 64 * NF; i += 256) hs[i] = h[(size_t)n0 * NF + i];
  __syncthreads();
  int rg = tid >> 4, cg = tid & 15;
  int r0 = rg * 4, c0 = cg * 5;
  float acc[4][5] = {};
  for (int k = 0; k < NF; ++k) {
    float wv[5];
#pragma unroll
    for (int j = 0; j < 5; ++j) wv[j] = (c0 + j < NF) ? Ws[k * NF + c0 + j] : 0.f;
#pragma unroll
    for (int i = 0; i < 4; ++i) {
      float hv = hs[(r0 + i) * NF + k];
#pragma unroll
      for (int j = 0; j < 5; ++j) acc[i][j] += hv * wv[j];
    }
  }
  for (int i = 0; i < 4; ++i)
    for (int j = 0; j < 5; ++j) {
      int c = c0 + j;
      if (c < NF) t[(size_t)(n0 + r0 + i) * NF + c] = (unsigned short)f2bf_rn(acc[i][j]);
    }
}

// t = (h .* gate) @ W  (layers 2,3; h bf16), output bf16
__global__ __launch_bounds__(256) void k_gemm_bf16(const unsigned short* __restrict__ h,
                                                   const float* __restrict__ gate,
                                                   const float* __restrict__ W,
                                                   unsigned short* __restrict__ t) {
  __shared__ float hs[64 * NF];
  __shared__ float Ws[NF * NF];
  int n0 = blockIdx.x * 64;
  int tid = threadIdx.x;
  for (int i = tid; i < NF * NF; i += 256) Ws[i] = W[i];
  for (int i = tid; i < 64 * NF; i += 256) {
    int r = i / NF;
    hs[i] = bf2f(h[(size_t)n0 * NF + i]) * gate[n0 + r];
  }
  __syncthreads();
  int rg = tid >> 4, cg = tid & 15;
  int r0 = rg * 4, c0 = cg * 5;
  float acc[4][5] = {};
  for (int k = 0; k < NF; ++k) {
    float wv[5];
#pragma unroll
    for (int j = 0; j < 5; ++j) wv[j] = (c0 + j < NF) ? Ws[k * NF + c0 + j] : 0.f;
#pragma unroll
    for (int i = 0; i < 4; ++i) {
      float hv = hs[(r0 + i) * NF + k];
#pragma unroll
      for (int j = 0; j < 5; ++j) acc[i][j] += hv * wv[j];
    }
  }
  for (int i = 0; i < 4; ++i)
    for (int j = 0; j < 5; ++j) {
      int c = c0 + j;
      if (c < NF) t[(size_t)(n0 + r0 + i) * NF + c] = (unsigned short)f2bf_rn(acc[i][j]);
    }
}

// out = relu(bn(agg + t*selfc + b)); also spre = out . Wp  (one wave per node)
// Row = 39 uints (78 bf16). One global_load_dword per edge; lanes 39-63 clamp.
__global__ __launch_bounds__(256) void k_agg(const unsigned* __restrict__ tu, const int* __restrict__ offs,
                                             const int* __restrict__ cnt, const int* __restrict__ csr,
                                             const float* __restrict__ cf, const float* __restrict__ dis,
                                             const float* __restrict__ bias, const float* __restrict__ bn,
                                             const float* __restrict__ Wp,
                                             unsigned* __restrict__ hout, float* __restrict__ spre) {
  int wave = threadIdx.x >> 6, lane = threadIdx.x & 63;
  int n = blockIdx.x * 4 + wave;
  float disn = dis[n];
  int st = offs[n], cn = cnt[n];
  int cn1 = cn < 64 ? cn : 64;
  int sIdx = 0; float sCoef = 0.f;
  if (lane < cn1) {
    sIdx = csr[st + lane] * 39;
    sCoef = cf[st + lane];
  }
  int lc = lane < 39 ? lane : 38;
  int rowu = n * 39;
  float selfc = disn * disn;
  unsigned su = tu[rowu + lc];
  float a0e = __uint_as_float(su << 16) * selfc;
  float a1e = __uint_as_float(su & 0xffff0000u) * selfc;
  float a0o = 0.f, a1o = 0.f;
  int j = 0;
#pragma unroll 4
  for (; j + 2 <= cn1; j += 2) {
    int sb0 = __shfl(sIdx, j);     float c0 = __shfl(sCoef, j);
    int sb1 = __shfl(sIdx, j + 1); float c1 = __shfl(sCoef, j + 1);
    unsigned u0 = tu[sb0 + lc];
    unsigned u1 = tu[sb1 + lc];
    a0e += c0 * __uint_as_float(u0 << 16);
    a1e += c0 * __uint_as_float(u0 & 0xffff0000u);
    a0o += c1 * __uint_as_float(u1 << 16);
    a1o += c1 * __uint_as_float(u1 & 0xffff0000u);
  }
  if (j < cn1) {
    int sb = __shfl(sIdx, j); float c = __shfl(sCoef, j);
    unsigned u = tu[sb + lc];
    a0e += c * __uint_as_float(u << 16);
    a1e += c * __uint_as_float(u & 0xffff0000u);
  }
  for (j = 64; j < cn; ++j) {  // safety tail, effectively never taken
    int sb = csr[st + j] * 39; float c = cf[st + j];
    unsigned u = tu[sb + lc];
    a0e += c * __uint_as_float(u << 16);
    a1e += c * __uint_as_float(u & 0xffff0000u);
  }
  float a0 = a0e + a0o, a1 = a1e + a1o;
  float h0 = 0.f, h1 = 0.f;
  float2 wp = make_float2(0.f, 0.f);
  if (lane < 39) {
    float2 bi = *reinterpret_cast<const float2*>(bias + 2 * lane);
    float2 gm = *reinterpret_cast<const float2*>(bn + 2 * lane);
    float2 bt = *reinterpret_cast<const float2*>(bn + NF + 2 * lane);
    h0 = fmaxf(0.f, gm.x * BNR * (a0 + bi.x) + bt.x);
    h1 = fmaxf(0.f, gm.y * BNR * (a1 + bi.y) + bt.y);
    hout[rowu + lane] = f2bf_rn(h0) | (f2bf_rn(h1) << 16);
    wp = *reinterpret_cast<const float2*>(Wp + 2 * lane);
  }
  float p = h0 * wp.x + h1 * wp.y;
  p = wave_red_sum(p);
  if (lane == 0) spre[n] = p;
}

__global__ void k_gate(const float* __restrict__ spre, const int* __restrict__ offs,
                       const int* __restrict__ cnt, const int* __restrict__ csr,
                       const float* __restrict__ cf, const float* __restrict__ dis,
                       const float* __restrict__ bp, float* __restrict__ gate) {
  int n = blockIdx.x * 256 + threadIdx.x;
  if (n >= N_NODES) return;
  float disn = dis[n];
  float s = bp[0] + disn * disn * spre[n];
  int st = offs[n], cn = cnt[n];
#pragma unroll 4
  for (int j = 0; j < cn; ++j) {
    s += cf[st + j] * spre[csr[st + j]];
  }
  gate[n] = tanhf(s);
}

// per-graph max & mean over contiguous 256-node segments; accumulate x1+x2+x3
__global__ __launch_bounds__(128) void k_readout(const unsigned short* __restrict__ h,
                                                 const float* __restrict__ gate,
                                                 float* __restrict__ xsum, int accum) {
  __shared__ float gl[256];
  int b = blockIdx.x, tid = threadIdx.x;
  for (int i = tid; i < 256; i += 128) gl[i] = gate[b * 256 + i];
  __syncthreads();
  if (tid >= NF) return;
  float mx = -1e30f, sm = 0.f;
  const unsigned short* hp = h + (size_t)b * 256 * NF + tid;
  for (int nn = 0; nn < 256; ++nn) {
    float v = bf2f(hp[(size_t)nn * NF]) * gl[nn];
    mx = fmaxf(mx, v);
    sm += v;
  }
  float mean = sm * (1.f / 256.f);
  if (accum) {
    xsum[b * 156 + tid] += mx;
    xsum[b * 156 + NF + tid] += mean;
  } else {
    xsum[b * 156 + tid] = mx;
    xsum[b * 156 + NF + tid] = mean;
  }
}

// g = relu(bn4((x1+x2+x3) @ fcg1_W + fcg1_b))
__global__ __launch_bounds__(128) void k_fcg(const float* __restrict__ xsum, const float* __restrict__ W,
                                             const float* __restrict__ bias, const float* __restrict__ bn,
                                             float* __restrict__ g) {
  __shared__ float xs[156];
  int b = blockIdx.x, tid = threadIdx.x;
  for (int i = tid; i < 156; i += 128) xs[i] = xsum[b * 156 + i];
  __syncthreads();
  float acc = bias[tid];
  for (int i = 0; i < 156; ++i) acc += xs[i] * W[i * 128 + tid];
  g[b * 128 + tid] = fmaxf(0.f, bn[tid] * BNR * acc + bn[128 + tid]);
}

// ---------------- protein branch ----------------
// Wt[i*384 + oc*3 + k] = c1W[oc*3000 + i*3 + k]
__global__ void k_transpose_w(const float* __restrict__ c1W, float* __restrict__ Wt) {
  int idx = blockIdx.x * 256 + threadIdx.x;
  if (idx >= 384000) return;
  int i = idx / 384;
  int r = idx - i * 384;
  int oc = r / 3, k = r - oc * 3;
  Wt[idx] = c1W[oc * 3000 + i * 3 + k];
}

// conv1 via vocab bucketing.
// 2a: counting-sort positions by vocab (INT LDS atomics, native); border sorted by v.
// 2b: outer loop over buckets; inner loop unroll-4 dual-acc (pipelined loads).
// 3:  el padded to stride 132; 9x ds_read_b128 broadcast per v.
__global__ __launch_bounds__(512) void k_conv1(const float* __restrict__ Wt, const int* __restrict__ target,
                                               const float* __restrict__ emb, const float* __restrict__ c1b,
                                               const float* __restrict__ bnx, float* __restrict__ O) {
  __shared__ float G[26 * 384];
  __shared__ float el[26 * 132];
  __shared__ int tg[1000];
  __shared__ int border[1000];
  __shared__ int cnt26[26], boff[27], cur26[26];
  int b = blockIdx.x, tid = threadIdx.x;
  if (tid < 26) cnt26[tid] = 0;
  for (int i = tid; i < 26 * 132; i += 512) {
    int v = i / 132, hp = i - v * 132;
    el[i] = (hp >= 1 && hp <= 128) ? emb[v * 128 + hp - 1] : 0.f;
  }
  for (int i = tid; i < 1000; i += 512) tg[i] = target[b * 1000 + i];
  __syncthreads();
  for (int i = tid; i < 1000; i += 512) atomicAdd(&cnt26[tg[i]], 1);
  __syncthreads();
  if (tid == 0) {
    int run = 0;
    for (int v = 0; v < 26; ++v) { boff[v] = run; cur26[v] = run; run += cnt26[v]; }
    boff[26] = run;
  }
  __syncthreads();
  for (int i = tid; i < 1000; i += 512) {
    int v = tg[i];
    int slot = atomicAdd(&cur26[v], 1);
    border[slot] = i;
  }
  __syncthreads();
  if (tid < 384) {
    for (int v = 0; v < 26; ++v) {
      int k0 = boff[v], k1 = boff[v + 1];
      float ae = 0.f, ao = 0.f;
      int k = k0;
#pragma unroll 4
      for (; k + 2 <= k1; k += 2) {
        int p0 = border[k];
        int p1 = border[k + 1];
        ae += Wt[(size_t)p0 * 384 + tid];
        ao += Wt[(size_t)p1 * 384 + tid];
      }
      if (k < k1) ae += Wt[(size_t)border[k] * 384 + tid];
      G[v * 384 + tid] = ae + ao;
    }
  }
  __syncthreads();
  int oc = tid & 127, q = tid >> 7;
  int h0 = q * 32;
  float acc[32];
#pragma unroll
  for (int j = 0; j < 32; ++j) acc[j] = 0.f;
  for (int v = 0; v < 26; ++v) {
    float g0 = G[v * 384 + oc * 3 + 0];
    float g1 = G[v * 384 + oc * 3 + 1];
    float g2 = G[v * 384 + oc * 3 + 2];
    float4 buf[9];
    const float4* ep = reinterpret_cast<const float4*>(&el[v * 132 + h0]);
#pragma unroll
    for (int r = 0; r < 9; ++r) buf[r] = ep[r];
    const float* bf = reinterpret_cast<const float*>(buf);
#pragma unroll
    for (int j = 0; j < 32; ++j)
      acc[j] += g0 * bf[j] + g1 * bf[j + 1] + g2 * bf[j + 2];
  }
  float bia = c1b[oc];
  float sc = bnx[oc] * BNR, bt = bnx[128 + oc];
  float* outp = O + (size_t)b * 16384 + oc * 128 + h0;
#pragma unroll
  for (int j = 0; j < 32; ++j) acc[j] = fmaxf(0.f, sc * (acc[j] + bia) + bt);
#pragma unroll
  for (int j = 0; j < 8; ++j)
    *reinterpret_cast<float4*>(outp + 4 * j) =
        make_float4(acc[4 * j], acc[4 * j + 1], acc[4 * j + 2], acc[4 * j + 3]);
}

// conv2: b128 bulk window reads (10 float4 per input channel), FMA from registers.
__global__ __launch_bounds__(256) void k_conv2(const float* __restrict__ X, const float* __restrict__ W,
                                               const float* __restrict__ bias, const float* __restrict__ bnx,
                                               float* __restrict__ O) {
  __shared__ float xl[128 * 136];
  int b = blockIdx.x, tid = threadIdx.x;
  for (int i = tid; i < 128 * 32; i += 256) {
    int row = i >> 5, c4 = (i & 31) * 4;
    float4 v = *reinterpret_cast<const float4*>(X + (size_t)b * 16384 + row * 128 + c4);
    *reinterpret_cast<float4*>(&xl[row * 136 + 4 + c4]) = v;
  }
  if (tid < 128) { xl[tid * 136 + 3] = 0.f; xl[tid * 136 + 132] = 0.f; }
  __syncthreads();
  int oc = tid & 63, q = tid >> 6;
  int h0 = q * 32;
  float acc[32];
#pragma unroll
  for (int j = 0; j < 32; ++j) acc[j] = 0.f;
  const float* wp = W + oc * 384;
  for (int i = 0; i < 128; ++i) {
    float w0 = wp[i * 3], w1 = wp[i * 3 + 1], w2 = wp[i * 3 + 2];
    float4 buf[10];
    const float4* xp = reinterpret_cast<const float4*>(&xl[i * 136 + h0]);
#pragma unroll
    for (int r = 0; r < 10; ++r) buf[r] = xp[r];
    const float* bf = reinterpret_cast<const float*>(buf);
#pragma unroll
    for (int j = 0; j < 32; ++j)
      acc[j] += w0 * bf[3 + j] + w1 * bf[4 + j] + w2 * bf[5 + j];
  }
  float bia = bias[oc], sc = bnx[oc] * BNR, bt = bnx[64 + oc];
  float* outp = O + (size_t)b * 8192 + oc * 128 + h0;
#pragma unroll
  for (int j = 0; j < 32; ++j) acc[j] = fmaxf(0.f, sc * (acc[j] + bia) + bt);
#pragma unroll
  for (int j = 0; j < 8; ++j)
    *reinterpret_cast<float4*>(outp + 4 * j) =
        make_float4(acc[4 * j], acc[4 * j + 1], acc[4 * j + 2], acc[4 * j + 3]);
}

// conv3: b128 bulk window reads (6 float4 per input channel).
__global__ __launch_bounds__(256) void k_conv3(const float* __restrict__ X, const float* __restrict__ W,
                                               const float* __restrict__ bias, const float* __restrict__ bnx,
                                               float* __restrict__ O) {
  __shared__ float xl[64 * 136];
  int b = blockIdx.x, tid = threadIdx.x;
  for (int i = tid; i < 64 * 32; i += 256) {
    int row = i >> 5, c4 = (i & 31) * 4;
    float4 v = *reinterpret_cast<const float4*>(X + (size_t)b * 8192 + row * 128 + c4);
    *reinterpret_cast<float4*>(&xl[row * 136 + 4 + c4]) = v;
  }
  if (tid < 64) { xl[tid * 136 + 3] = 0.f; xl[tid * 136 + 132] = 0.f; }
  __syncthreads();
  int oc = tid & 31, q = tid >> 5;  // 0..7
  int h0 = q * 16;
  float acc[16];
#pragma unroll
  for (int j = 0; j < 16; ++j) acc[j] = 0.f;
  const float* wp = W + oc * 192;
  for (int i = 0; i < 64; ++i) {
    float w0 = wp[i * 3], w1 = wp[i * 3 + 1], w2 = wp[i * 3 + 2];
    float4 buf[6];
    const float4* xp = reinterpret_cast<const float4*>(&xl[i * 136 + h0]);
#pragma unroll
    for (int r = 0; r < 6; ++r) buf[r] = xp[r];
    const float* bf = reinterpret_cast<const float*>(buf);
#pragma unroll
    for (int j = 0; j < 16; ++j)
      acc[j] += w0 * bf[3 + j] + w1 * bf[4 + j] + w2 * bf[5 + j];
  }
  float bia = bias[oc], sc = bnx[oc] * BNR, bt = bnx[32 + oc];
  float* outp = O + (size_t)b * 4096 + oc * 128 + h0;
#pragma unroll
  for (int j = 0; j < 16; ++j) acc[j] = fmaxf(0.f, sc * (acc[j] + bia) + bt);
#pragma unroll
  for (int j = 0; j < 4; ++j)
    *reinterpret_cast<float4*>(outp + 4 * j) =
        make_float4(acc[4 * j], acc[4 * j + 1], acc[4 * j + 2], acc[4 * j + 3]);
}

// ---- fxt: [512,4096] @ [4096,128], K-split 8 ways for parallelism ----
__global__ __launch_bounds__(128) void k_fxt_part(const float* __restrict__ P, const float* __restrict__ W,
                                                  float* __restrict__ part) {
  __shared__ float pl[8 * 512];
  int bblk = blockIdx.x >> 3, kc = blockIdx.x & 7;
  int b0 = bblk * 8, tid = threadIdx.x;
  for (int i = tid; i < 8 * 512; i += 128) {
    int bb = i >> 9, k = i & 511;
    pl[i] = P[(size_t)(b0 + bb) * 4096 + kc * 512 + k];
  }
  __syncthreads();
  float acc[8] = {};
  const float* wp = W + (size_t)kc * 512 * 128 + tid;
  for (int k = 0; k < 512; ++k) {
    float w = wp[(size_t)k * 128];
#pragma unroll
    for (int bb = 0; bb < 8; ++bb) acc[bb] += pl[bb * 512 + k] * w;
  }
#pragma unroll
  for (int bb = 0; bb < 8; ++bb)
    part[((size_t)kc * 512 + b0 + bb) * 128 + tid] = acc[bb];
}

// xt = bn6(relu(sum_kc part + fxt_b))   (bn AFTER relu)
__global__ __launch_bounds__(256) void k_fxt_red(const float* __restrict__ part, const float* __restrict__ bias,
                                                 const float* __restrict__ bn, float* __restrict__ xt) {
  int idx = blockIdx.x * 256 + threadIdx.x;  // 512*128
  int j = idx & 127;
  float s = 0.f;
#pragma unroll
  for (int kc = 0; kc < 8; ++kc) s += part[(size_t)kc * 65536 + idx];
  xt[idx] = bn[j] * BNR * fmaxf(0.f, s + bias[j]) + bn[128 + j];
}

// xc1 = bn7(relu([g|xt] @ fc1W + fc1b)); grid 512 = (bblk 0..127)x(jb 0..3)
__global__ __launch_bounds__(256) void k_fc1(const float* __restrict__ g, const float* __restrict__ xt,
                                             const float* __restrict__ W, const float* __restrict__ bias,
                                             const float* __restrict__ bn, float* __restrict__ out) {
  __shared__ float al[4 * 256];
  int bblk = blockIdx.x >> 2, jb = blockIdx.x & 3;
  int b0 = bblk * 4, tid = threadIdx.x;
  int j = jb * 256 + tid;
  for (int i = tid; i < 4 * 256; i += 256) {
    int bb = i >> 8, c = i & 255;
    al[i] = (c < 128) ? g[(b0 + bb) * 128 + c] : xt[(b0 + bb) * 128 + c - 128];
  }
  __syncthreads();
  float acc[4] = {};
  for (int i = 0; i < 256; ++i) {
    float w = W[(size_t)i * 1024 + j];
#pragma unroll
    for (int bb = 0; bb < 4; ++bb) acc[bb] += al[bb * 256 + i] * w;
  }
  float bi = bias[j], sc = bn[j] * BNR, bt = bn[1024 + j];
#pragma unroll
  for (int bb = 0; bb < 4; ++bb)
    out[(size_t)(b0 + bb) * 1024 + j] = sc * fmaxf(0.f, acc[bb] + bi) + bt;
}

// xc2 = bn8(relu(xc1 @ fc2W + fc2b)); grid 256 = (bblk 0..127)x(jb 0..1)
__global__ __launch_bounds__(256) void k_fc2(const float* __restrict__ xc1, const float* __restrict__ W,
                                             const float* __restrict__ bias, const float* __restrict__ bn,
                                             float* __restrict__ out) {
  __shared__ float al[4 * 1024];
  int bblk = blockIdx.x >> 1, jb = blockIdx.x & 1;
  int b0 = bblk * 4, tid = threadIdx.x;
  int j = jb * 256 + tid;
  for (int i = tid; i < 4 * 1024; i += 256)
    al[i] = xc1[(size_t)(b0 + (i >> 10)) * 1024 + (i & 1023)];
  __syncthreads();
  float acc[4] = {};
  for (int i = 0; i < 1024; ++i) {
    float w = W[(size_t)i * 512 + j];
#pragma unroll
    for (int bb = 0; bb < 4; ++bb) acc[bb] += al[bb * 1024 + i] * w;
  }
  float bi = bias[j], sc = bn[j] * BNR, bt = bn[512 + j];
#pragma unroll
  for (int bb = 0; bb < 4; ++bb)
    out[(size_t)(b0 + bb) * 512 + j] = sc * fmaxf(0.f, acc[bb] + bi) + bt;
}

__global__ __launch_bounds__(256) void k_out(const float* __restrict__ xc2, const float* __restrict__ W,
                                             const float* __restrict__ ob, float* __restrict__ out) {
  __shared__ float red[4];
  int b = blockIdx.x, tid = threadIdx.x;
  float v = xc2[(size_t)b * 512 + tid] * W[tid] + xc2[(size_t)b * 512 + 256 + tid] * W[256 + tid];
  v = wave_red_sum(v);
  int wave = tid >> 6, lane = tid & 63;
  if (lane == 0) red[wave] = v;
  __syncthreads();
  if (tid == 0) out[b] = red[0] + red[1] + red[2] + red[3] + ob[0];
}

extern "C" void kernel_launch(void* const* d_in, const int* in_sizes, int n_in,
                              void* d_out, int out_size, void* d_ws, size_t ws_size,
                              hipStream_t stream) {
  (void)in_sizes; (void)n_in; (void)out_size; (void)ws_size;
  const float* x      = (const float*)d_in[0];
  const int*   eidx   = (const int*)d_in[1];
  const int*   src    = eidx;
  const int*   dst    = eidx + N_EDGES;
  const int*   target = (const int*)d_in[3];
  const float* W1 = (const float*)d_in[4];  const float* b1 = (const float*)d_in[5];
  const float* bn1 = (const float*)d_in[6]; const float* Wp1 = (const float*)d_in[7];
  const float* bp1 = (const float*)d_in[8];
  const float* W2 = (const float*)d_in[9];  const float* b2 = (const float*)d_in[10];
  const float* bn2 = (const float*)d_in[11]; const float* Wp2 = (const float*)d_in[12];
  const float* bp2 = (const float*)d_in[13];
  const float* W3 = (const float*)d_in[14]; const float* b3 = (const float*)d_in[15];
  const float* bn3 = (const float*)d_in[16]; const float* Wp3 = (const float*)d_in[17];
  const float* bp3 = (const float*)d_in[18];
  const float* fcg1_W = (const float*)d_in[19]; const float* fcg1_b = (const float*)d_in[20];
  const float* bn4 = (const float*)d_in[21];
  const float* emb = (const float*)d_in[22];
  const float* c1W = (const float*)d_in[23]; const float* c1b = (const float*)d_in[24];
  const float* bnx1 = (const float*)d_in[25];
  const float* c2W = (const float*)d_in[26]; const float* c2b = (const float*)d_in[27];
  const float* bnx2 = (const float*)d_in[28];
  const float* c3W = (const float*)d_in[29]; const float* c3b = (const float*)d_in[30];
  const float* bnx3 = (const float*)d_in[31];
  const float* fxt_W = (const float*)d_in[32]; const float* fxt_b = (const float*)d_in[33];
  const float* bn6 = (const float*)d_in[34];
  const float* fc1W = (const float*)d_in[35]; const float* fc1b = (const float*)d_in[36];
  const float* bn7 = (const float*)d_in[37];
  const float* fc2W = (const float*)d_in[38]; const float* fc2b = (const float*)d_in[39];
  const float* bn8 = (const float*)d_in[40];
  const float* outW = (const float*)d_in[41]; const float* outb = (const float*)d_in[42];

  char* ws = (char*)d_ws;
  size_t off = 0;
  auto alloc = [&](size_t bytes) -> void* {
    void* p = ws + off;
    off += (bytes + 255) & ~(size_t)255;
    return p;
  };
  float* dis   = (float*)alloc((size_t)N_NODES * 4);
  int*   cnt   = (int*)alloc((size_t)N_NODES * 4);
  int*   cursor= (int*)alloc((size_t)N_NODES * 4);
  int*   offs  = (int*)alloc((size_t)N_NODES * 4);
  int*   bsum  = (int*)alloc(1024);
  int*   csr   = (int*)alloc((size_t)N_EDGES * 4);
  float* cf    = (float*)alloc((size_t)N_EDGES * 4);
  float* h_a   = (float*)alloc((size_t)N_NODES * NF * 4);   // region; holds bf16 h rows (39 uints)
  float* h_b   = (float*)alloc((size_t)N_NODES * NF * 4);
  float* tbuf  = (float*)alloc((size_t)N_NODES * NF * 4);   // region; holds bf16 t
  float* gate  = (float*)alloc((size_t)N_NODES * 4);
  float* spre  = (float*)alloc((size_t)N_NODES * 4);
  float* xsum  = (float*)alloc(512 * 156 * 4);
  float* gbuf  = (float*)alloc(512 * 128 * 4);
  float* xt    = (float*)alloc(512 * 128 * 4);
  float* xc1   = (float*)alloc(512 * 1024 * 4);
  float* xc2   = (float*)alloc(512 * 512 * 4);
  unsigned short* tb = (unsigned short*)tbuf;
  unsigned* tu = (unsigned*)tbuf;
  unsigned* ha_u = (unsigned*)h_a;  unsigned short* ha_s = (unsigned short*)h_a;
  unsigned* hb_u = (unsigned*)h_b;  unsigned short* hb_s = (unsigned short*)h_b;
  // protein-branch aliases (GNN big buffers are dead by then)
  float* O1 = h_a;                      // 512*128*128 = 33.5 MB <= 40.9 MB
  float* O2 = h_b;                      // 512*64*128  = 16.8 MB
  float* Wt = tbuf;                     // 1000*384    = 1.54 MB
  float* P  = tbuf + 524288;            // +2 MB: 512*32*128 = 8.4 MB
  float* fxt_part = h_a;                // 8*512*128 = 2 MB (O1 dead after conv2)

  hipMemsetAsync(cnt, 0, (size_t)N_NODES * 4, stream);
  hipMemsetAsync(cursor, 0, (size_t)N_NODES * 4, stream);

  k_count<<<N_EDGES / 256, 256, 0, stream>>>(dst, cnt);
  k_dis<<<N_NODES / 256, 256, 0, stream>>>(cnt, dis);
  k_scan1<<<N_NODES / 512, 512, 0, stream>>>(cnt, offs, bsum);
  k_scan2<<<1, 256, 0, stream>>>(bsum);
  k_scan3<<<N_NODES / 512, 512, 0, stream>>>(offs, bsum);
  k_fill<<<N_EDGES / 256, 256, 0, stream>>>(src, dst, offs, cursor, dis, csr, cf);

  // layer 1
  k_gemm_f32<<<N_NODES / 64, 256, 0, stream>>>(x, W1, tb);
  k_agg<<<N_NODES / 4, 256, 0, stream>>>(tu, offs, cnt, csr, cf, dis, b1, bn1, Wp1, ha_u, spre);
  k_gate<<<N_NODES / 256, 256, 0, stream>>>(spre, offs, cnt, csr, cf, dis, bp1, gate);
  k_readout<<<NB, 128, 0, stream>>>(ha_s, gate, xsum, 0);
  // layer 2
  k_gemm_bf16<<<N_NODES / 64, 256, 0, stream>>>(ha_s, gate, W2, tb);
  k_agg<<<N_NODES / 4, 256, 0, stream>>>(tu, offs, cnt, csr, cf, dis, b2, bn2, Wp2, hb_u, spre);
  k_gate<<<N_NODES / 256, 256, 0, stream>>>(spre, offs, cnt, csr, cf, dis, bp2, gate);
  k_readout<<<NB, 128, 0, stream>>>(hb_s, gate, xsum, 1);
  // layer 3
  k_gemm_bf16<<<N_NODES / 64, 256, 0, stream>>>(hb_s, gate, W3, tb);
  k_agg<<<N_NODES / 4, 256, 0, stream>>>(tu, offs, cnt, csr, cf, dis, b3, bn3, Wp3, ha_u, spre);
  k_gate<<<N_NODES / 256, 256, 0, stream>>>(spre, offs, cnt, csr, cf, dis, bp3, gate);
  k_readout<<<NB, 128, 0, stream>>>(ha_s, gate, xsum, 1);

  k_fcg<<<NB, 128, 0, stream>>>(xsum, fcg1_W, fcg1_b, bn4, gbuf);

  // protein branch (reuses h_a/h_b/tbuf regions — all GNN reads complete above)
  k_transpose_w<<<1500, 256, 0, stream>>>(c1W, Wt);
  k_conv1<<<NB, 512, 0, stream>>>(Wt, target, emb, c1b, bnx1, O1);
  k_conv2<<<NB, 256, 0, stream>>>(O1, c2W, c2b, bnx2, O2);
  k_conv3<<<NB, 256, 0, stream>>>(O2, c3W, c3b, bnx3, P);
  // O1 (h_a) is dead after conv2 -> reuse for fxt partials
  k_fxt_part<<<512, 128, 0, stream>>>(P, fxt_W, fxt_part);
  k_fxt_red<<<256, 256, 0, stream>>>(fxt_part, fxt_b, bn6, xt);

  k_fc1<<<512, 256, 0, stream>>>(gbuf, xt, fc1W, fc1b, bn7, xc1);
  k_fc2<<<256, 256, 0, stream>>>(xc1, fc2W, fc2b, bn8, xc2);
  k_out<<<NB, 256, 0, stream>>>(xc2, outW, outb, (float*)d_out);
}

// Round 11
// 752.515 us; speedup vs baseline: 1.1879x; 1.0113x over previous
//
#include <hip/hip_runtime.h>
#include <hip/hip_bf16.h>
#include <cstddef>

#define N_NODES 131072
#define N_EDGES 1048576
#define NF 78
#define NB 512
#define BNR 0.9999950000374996f  // 1/sqrt(1+1e-5)

typedef float v2f __attribute__((ext_vector_type(2)));

__device__ __forceinline__ float wave_red_sum(float v) {
  for (int off = 32; off > 0; off >>= 1) v += __shfl_down(v, off);
  return v;
}

__device__ __forceinline__ float bf2f(unsigned short u) {
  return __uint_as_float(((unsigned)u) << 16);
}

__device__ __forceinline__ unsigned f2bf_rn(float x) {  // round-to-nearest-even bf16 bits
  unsigned u = __float_as_uint(x);
  return (u + 0x7fffu + ((u >> 16) & 1u)) >> 16;
}

__device__ __forceinline__ unsigned char f2fp8(float x) {  // OCP e4m3 via HW cvt
  int p = __builtin_amdgcn_cvt_pk_fp8_f32(x, x, 0, false);
  return (unsigned char)(p & 0xff);
}

// ---------------- graph setup ----------------
__global__ void k_count(const int* __restrict__ dst, int* __restrict__ cnt) {
  int e = blockIdx.x * 256 + threadIdx.x;
  if (e < N_EDGES) atomicAdd(&cnt[dst[e]], 1);
}

__global__ void k_dis(const int* __restrict__ cnt, float* __restrict__ dis) {
  int n = blockIdx.x * 256 + threadIdx.x;
  if (n < N_NODES) dis[n] = rsqrtf(1.0f + (float)cnt[n]);
}

__global__ void k_scan1(const int* __restrict__ cnt, int* __restrict__ offs, int* __restrict__ bsum) {
  __shared__ int s[512];
  int gid = blockIdx.x * 512 + threadIdx.x;
  int v = cnt[gid];
  s[threadIdx.x] = v; __syncthreads();
  for (int off = 1; off < 512; off <<= 1) {
    int t = (threadIdx.x >= off) ? s[threadIdx.x - off] : 0;
    __syncthreads();
    s[threadIdx.x] += t;
    __syncthreads();
  }
  offs[gid] = s[threadIdx.x] - v;               // exclusive
  if (threadIdx.x == 511) bsum[blockIdx.x] = s[511];
}

__global__ void k_scan2(int* __restrict__ bsum) {  // 1 block, 256 threads
  __shared__ int s[256];
  int v = bsum[threadIdx.x];
  s[threadIdx.x] = v; __syncthreads();
  for (int off = 1; off < 256; off <<= 1) {
    int t = (threadIdx.x >= off) ? s[threadIdx.x - off] : 0;
    __syncthreads();
    s[threadIdx.x] += t;
    __syncthreads();
  }
  bsum[threadIdx.x] = s[threadIdx.x] - v;       // exclusive
}

__global__ void k_scan3(int* __restrict__ offs, const int* __restrict__ bsum) {
  int gid = blockIdx.x * 512 + threadIdx.x;
  offs[gid] += bsum[blockIdx.x];
}

__global__ void k_fill(const int* __restrict__ src, const int* __restrict__ dst,
                       const int* __restrict__ offs, int* __restrict__ cursor,
                       const float* __restrict__ dis, int* __restrict__ csr,
                       float* __restrict__ cf) {
  int e = blockIdx.x * 256 + threadIdx.x;
  if (e < N_EDGES) {
    int s = src[e], d = dst[e];
    int pos = offs[d] + atomicAdd(&cursor[d], 1);
    csr[pos] = s;
    cf[pos] = dis[s] * dis[d];
  }
}

// ---------------- GCN layer ----------------
// t = h @ W  (layer 1, f32 input, no gate), output fp8 e4m3, row stride 128B
__global__ __launch_bounds__(256) void k_gemm_f32(const float* __restrict__ h,
                                                  const float* __restrict__ W,
                                                  unsigned char* __restrict__ t8) {
  __shared__ float hs[64 * NF];
  __shared__ float Ws[NF * NF];
  int n0 = blockIdx.x * 64;
  int tid = threadIdx.x;
  for (int i = tid; i < NF * NF; i += 256) Ws[i] = W[i];
  for (int i = tid; i < 64 * NF; i += 256) hs[i] = h[(size_t)n0 * NF + i];
  __syncthreads();
  int rg = tid >> 4, cg = tid & 15;
  int r0 = rg * 4, c0 = cg * 5;
  float acc[4][5] = {};
  for (int k = 0; k < NF; ++k) {
    float wv[5];
#pragma unroll
    for (int j = 0; j < 5; ++j) wv[j] = (c0 + j < NF) ? Ws[k * NF + c0 + j] : 0.f;
#pragma unroll
    for (int i = 0; i < 4; ++i) {
      float hv = hs[(r0 + i) * NF + k];
#pragma unroll
      for (int j = 0; j < 5; ++j) acc[i][j] += hv * wv[j];
    }
  }
  for (int i = 0; i < 4; ++i)
    for (int j = 0; j < 5; ++j) {
      int c = c0 + j;
      if (c < NF) t8[(size_t)(n0 + r0 + i) * 128 + c] = f2fp8(acc[i][j]);
    }
}

// t = (h .* gate) @ W  (layers 2,3; h bf16), output fp8
__global__ __launch_bounds__(256) void k_gemm_bf16(const unsigned short* __restrict__ h,
                                                   const float* __restrict__ gate,
                                                   const float* __restrict__ W,
                                                   unsigned char* __restrict__ t8) {
  __shared__ float hs[64 * NF];
  __shared__ float Ws[NF * NF];
  int n0 = blockIdx.x * 64;
  int tid = threadIdx.x;
  for (int i = tid; i < NF * NF; i += 256) Ws[i] = W[i];
  for (int i = tid; i < 64 * NF; i += 256) {
    int r = i / NF;
    hs[i] = bf2f(h[(size_t)n0 * NF + i]) * gate[n0 + r];
  }
  __syncthreads();
  int rg = tid >> 4, cg = tid & 15;
  int r0 = rg * 4, c0 = cg * 5;
  float acc[4][5] = {};
  for (int k = 0; k < NF; ++k) {
    float wv[5];
#pragma unroll
    for (int j = 0; j < 5; ++j) wv[j] = (c0 + j < NF) ? Ws[k * NF + c0 + j] : 0.f;
#pragma unroll
    for (int i = 0; i < 4; ++i) {
      float hv = hs[(r0 + i) * NF + k];
#pragma unroll
      for (int j = 0; j < 5; ++j) acc[i][j] += hv * wv[j];
    }
  }
  for (int i = 0; i < 4; ++i)
    for (int j = 0; j < 5; ++j) {
      int c = c0 + j;
      if (c < NF) t8[(size_t)(n0 + r0 + i) * 128 + c] = f2fp8(acc[i][j]);
    }
}

// out = relu(bn(agg + t*selfc + b)); also spre = out . Wp  (one wave per node)
// t rows: fp8, 128B-aligned (2 cache lines). Lane lc<39 reads ushort = 2 features,
// decoded with v_cvt_pk_f32_fp8. h output stays bf16.
__global__ __launch_bounds__(256) void k_agg(const unsigned short* __restrict__ t16, const int* __restrict__ offs,
                                             const int* __restrict__ cnt, const int* __restrict__ csr,
                                             const float* __restrict__ cf, const float* __restrict__ dis,
                                             const float* __restrict__ bias, const float* __restrict__ bn,
                                             const float* __restrict__ Wp,
                                             unsigned* __restrict__ hout, float* __restrict__ spre) {
  int wave = threadIdx.x >> 6, lane = threadIdx.x & 63;
  int n = blockIdx.x * 4 + wave;
  float disn = dis[n];
  int st = offs[n], cn = cnt[n];
  int cn1 = cn < 64 ? cn : 64;
  int sIdx = 0; float sCoef = 0.f;
  if (lane < cn1) {
    sIdx = csr[st + lane] * 64;   // row stride = 64 ushorts (128B)
    sCoef = cf[st + lane];
  }
  int lc = lane < 39 ? lane : 38;
  float selfc = disn * disn;
  unsigned su = t16[(size_t)n * 64 + lc];
  v2f sf = __builtin_amdgcn_cvt_pk_f32_fp8(su, false);
  float a0e = sf[0] * selfc;
  float a1e = sf[1] * selfc;
  float a0o = 0.f, a1o = 0.f;
  int j = 0;
#pragma unroll 4
  for (; j + 2 <= cn1; j += 2) {
    int sb0 = __shfl(sIdx, j);     float c0 = __shfl(sCoef, j);
    int sb1 = __shfl(sIdx, j + 1); float c1 = __shfl(sCoef, j + 1);
    unsigned u0 = t16[sb0 + lc];
    unsigned u1 = t16[sb1 + lc];
    v2f f0 = __builtin_amdgcn_cvt_pk_f32_fp8(u0, false);
    v2f f1 = __builtin_amdgcn_cvt_pk_f32_fp8(u1, false);
    a0e += c0 * f0[0];
    a1e += c0 * f0[1];
    a0o += c1 * f1[0];
    a1o += c1 * f1[1];
  }
  if (j < cn1) {
    int sb = __shfl(sIdx, j); float c = __shfl(sCoef, j);
    unsigned u = t16[sb + lc];
    v2f f = __builtin_amdgcn_cvt_pk_f32_fp8(u, false);
    a0e += c * f[0];
    a1e += c * f[1];
  }
  for (j = 64; j < cn; ++j) {  // safety tail, effectively never taken
    int sb = csr[st + j] * 64; float c = cf[st + j];
    unsigned u = t16[sb + lc];
    v2f f = __builtin_amdgcn_cvt_pk_f32_fp8(u, false);
    a0e += c * f[0];
    a1e += c * f[1];
  }
  float a0 = a0e + a0o, a1 = a1e + a1o;
  float h0 = 0.f, h1 = 0.f;
  float2 wp = make_float2(0.f, 0.f);
  if (lane < 39) {
    float2 bi = *reinterpret_cast<const float2*>(bias + 2 * lane);
    float2 gm = *reinterpret_cast<const float2*>(bn + 2 * lane);
    float2 bt = *reinterpret_cast<const float2*>(bn + NF + 2 * lane);
    h0 = fmaxf(0.f, gm.x * BNR * (a0 + bi.x) + bt.x);
    h1 = fmaxf(0.f, gm.y * BNR * (a1 + bi.y) + bt.y);
    hout[(size_t)n * 39 + lane] = f2bf_rn(h0) | (f2bf_rn(h1) << 16);
    wp = *reinterpret_cast<const float2*>(Wp + 2 * lane);
  }
  float p = h0 * wp.x + h1 * wp.y;
  p = wave_red_sum(p);
  if (lane == 0) spre[n] = p;
}

__global__ void k_gate(const float* __restrict__ spre, const int* __restrict__ offs,
                       const int* __restrict__ cnt, const int* __restrict__ csr,
                       const float* __restrict__ cf, const float* __restrict__ dis,
                       const float* __restrict__ bp, float* __restrict__ gate) {
  int n = blockIdx.x * 256 + threadIdx.x;
  if (n >= N_NODES) return;
  float disn = dis[n];
  float s = bp[0] + disn * disn * spre[n];
  int st = offs[n], cn = cnt[n];
#pragma unroll 4
  for (int j = 0; j < cn; ++j) {
    s += cf[st + j] * spre[csr[st + j]];
  }
  gate[n] = tanhf(s);
}

// per-graph max & mean over contiguous 256-node segments; accumulate x1+x2+x3
__global__ __launch_bounds__(128) void k_readout(const unsigned short* __restrict__ h,
                                                 const float* __restrict__ gate,
                                                 float* __restrict__ xsum, int accum) {
  __shared__ float gl[256];
  int b = blockIdx.x, tid = threadIdx.x;
  for (int i = tid; i < 256; i += 128) gl[i] = gate[b * 256 + i];
  __syncthreads();
  if (tid >= NF) return;
  float mx = -1e30f, sm = 0.f;
  const unsigned short* hp = h + (size_t)b * 256 * NF + tid;
  for (int nn = 0; nn < 256; ++nn) {
    float v = bf2f(hp[(size_t)nn * NF]) * gl[nn];
    mx = fmaxf(mx, v);
    sm += v;
  }
  float mean = sm * (1.f / 256.f);
  if (accum) {
    xsum[b * 156 + tid] += mx;
    xsum[b * 156 + NF + tid] += mean;
  } else {
    xsum[b * 156 + tid] = mx;
    xsum[b * 156 + NF + tid] = mean;
  }
}

// g = relu(bn4((x1+x2+x3) @ fcg1_W + fcg1_b))
__global__ __launch_bounds__(128) void k_fcg(const float* __restrict__ xsum, const float* __restrict__ W,
                                             const float* __restrict__ bias, const float* __restrict__ bn,
                                             float* __restrict__ g) {
  __shared__ float xs[156];
  int b = blockIdx.x, tid = threadIdx.x;
  for (int i = tid; i < 156; i += 128) xs[i] = xsum[b * 156 + i];
  __syncthreads();
  float acc = bias[tid];
  for (int i = 0; i < 156; ++i) acc += xs[i] * W[i * 128 + tid];
  g[b * 128 + tid] = fmaxf(0.f, bn[tid] * BNR * acc + bn[128 + tid]);
}

// ---------------- protein branch ----------------
// Wt[i*384 + oc*3 + k] = c1W[oc*3000 + i*3 + k]
__global__ void k_transpose_w(const float* __restrict__ c1W, float* __restrict__ Wt) {
  int idx = blockIdx.x * 256 + threadIdx.x;
  if (idx >= 384000) return;
  int i = idx / 384;
  int r = idx - i * 384;
  int oc = r / 3, k = r - oc * 3;
  Wt[idx] = c1W[oc * 3000 + i * 3 + k];
}

// conv1 via vocab bucketing (counting sort + bucket-outer register accumulate).
__global__ __launch_bounds__(512) void k_conv1(const float* __restrict__ Wt, const int* __restrict__ target,
                                               const float* __restrict__ emb, const float* __restrict__ c1b,
                                               const float* __restrict__ bnx, float* __restrict__ O) {
  __shared__ float G[26 * 384];
  __shared__ float el[26 * 132];
  __shared__ int tg[1000];
  __shared__ int border[1000];
  __shared__ int cnt26[26], boff[27], cur26[26];
  int b = blockIdx.x, tid = threadIdx.x;
  if (tid < 26) cnt26[tid] = 0;
  for (int i = tid; i < 26 * 132; i += 512) {
    int v = i / 132, hp = i - v * 132;
    el[i] = (hp >= 1 && hp <= 128) ? emb[v * 128 + hp - 1] : 0.f;
  }
  for (int i = tid; i < 1000; i += 512) tg[i] = target[b * 1000 + i];
  __syncthreads();
  for (int i = tid; i < 1000; i += 512) atomicAdd(&cnt26[tg[i]], 1);
  __syncthreads();
  if (tid == 0) {
    int run = 0;
    for (int v = 0; v < 26; ++v) { boff[v] = run; cur26[v] = run; run += cnt26[v]; }
    boff[26] = run;
  }
  __syncthreads();
  for (int i = tid; i < 1000; i += 512) {
    int v = tg[i];
    int slot = atomicAdd(&cur26[v], 1);
    border[slot] = i;
  }
  __syncthreads();
  if (tid < 384) {
    for (int v = 0; v < 26; ++v) {
      int k0 = boff[v], k1 = boff[v + 1];
      float ae = 0.f, ao = 0.f;
      int k = k0;
#pragma unroll 4
      for (; k + 2 <= k1; k += 2) {
        int p0 = border[k];
        int p1 = border[k + 1];
        ae += Wt[(size_t)p0 * 384 + tid];
        ao += Wt[(size_t)p1 * 384 + tid];
      }
      if (k < k1) ae += Wt[(size_t)border[k] * 384 + tid];
      G[v * 384 + tid] = ae + ao;
    }
  }
  __syncthreads();
  int oc = tid & 127, q = tid >> 7;
  int h0 = q * 32;
  float acc[32];
#pragma unroll
  for (int j = 0; j < 32; ++j) acc[j] = 0.f;
  for (int v = 0; v < 26; ++v) {
    float g0 = G[v * 384 + oc * 3 + 0];
    float g1 = G[v * 384 + oc * 3 + 1];
    float g2 = G[v * 384 + oc * 3 + 2];
    float4 buf[9];
    const float4* ep = reinterpret_cast<const float4*>(&el[v * 132 + h0]);
#pragma unroll
    for (int r = 0; r < 9; ++r) buf[r] = ep[r];
    const float* bf = reinterpret_cast<const float*>(buf);
#pragma unroll
    for (int j = 0; j < 32; ++j)
      acc[j] += g0 * bf[j] + g1 * bf[j + 1] + g2 * bf[j + 2];
  }
  float bia = c1b[oc];
  float sc = bnx[oc] * BNR, bt = bnx[128 + oc];
  float* outp = O + (size_t)b * 16384 + oc * 128 + h0;
#pragma unroll
  for (int j = 0; j < 32; ++j) acc[j] = fmaxf(0.f, sc * (acc[j] + bia) + bt);
#pragma unroll
  for (int j = 0; j < 8; ++j)
    *reinterpret_cast<float4*>(outp + 4 * j) =
        make_float4(acc[4 * j], acc[4 * j + 1], acc[4 * j + 2], acc[4 * j + 3]);
}

// conv2: b128 bulk window reads (10 float4 per input channel), FMA from registers.
__global__ __launch_bounds__(256) void k_conv2(const float* __restrict__ X, const float* __restrict__ W,
                                               const float* __restrict__ bias, const float* __restrict__ bnx,
                                               float* __restrict__ O) {
  __shared__ float xl[128 * 136];
  int b = blockIdx.x, tid = threadIdx.x;
  for (int i = tid; i < 128 * 32; i += 256) {
    int row = i >> 5, c4 = (i & 31) * 4;
    float4 v = *reinterpret_cast<const float4*>(X + (size_t)b * 16384 + row * 128 + c4);
    *reinterpret_cast<float4*>(&xl[row * 136 + 4 + c4]) = v;
  }
  if (tid < 128) { xl[tid * 136 + 3] = 0.f; xl[tid * 136 + 132] = 0.f; }
  __syncthreads();
  int oc = tid & 63, q = tid >> 6;
  int h0 = q * 32;
  float acc[32];
#pragma unroll
  for (int j = 0; j < 32; ++j) acc[j] = 0.f;
  const float* wp = W + oc * 384;
  for (int i = 0; i < 128; ++i) {
    float w0 = wp[i * 3], w1 = wp[i * 3 + 1], w2 = wp[i * 3 + 2];
    float4 buf[10];
    const float4* xp = reinterpret_cast<const float4*>(&xl[i * 136 + h0]);
#pragma unroll
    for (int r = 0; r < 10; ++r) buf[r] = xp[r];
    const float* bf = reinterpret_cast<const float*>(buf);
#pragma unroll
    for (int j = 0; j < 32; ++j)
      acc[j] += w0 * bf[3 + j] + w1 * bf[4 + j] + w2 * bf[5 + j];
  }
  float bia = bias[oc], sc = bnx[oc] * BNR, bt = bnx[64 + oc];
  float* outp = O + (size_t)b * 8192 + oc * 128 + h0;
#pragma unroll
  for (int j = 0; j < 32; ++j) acc[j] = fmaxf(0.f, sc * (acc[j] + bia) + bt);
#pragma unroll
  for (int j = 0; j < 8; ++j)
    *reinterpret_cast<float4*>(outp + 4 * j) =
        make_float4(acc[4 * j], acc[4 * j + 1], acc[4 * j + 2], acc[4 * j + 3]);
}

// conv3: b128 bulk window reads (6 float4 per input channel).
__global__ __launch_bounds__(256) void k_conv3(const float* __restrict__ X, const float* __restrict__ W,
                                               const float* __restrict__ bias, const float* __restrict__ bnx,
                                               float* __restrict__ O) {
  __shared__ float xl[64 * 136];
  int b = blockIdx.x, tid = threadIdx.x;
  for (int i = tid; i < 64 * 32; i += 256) {
    int row = i >> 5, c4 = (i & 31) * 4;
    float4 v = *reinterpret_cast<const float4*>(X + (size_t)b * 8192 + row * 128 + c4);
    *reinterpret_cast<float4*>(&xl[row * 136 + 4 + c4]) = v;
  }
  if (tid < 64) { xl[tid * 136 + 3] = 0.f; xl[tid * 136 + 132] = 0.f; }
  __syncthreads();
  int oc = tid & 31, q = tid >> 5;  // 0..7
  int h0 = q * 16;
  float acc[16];
#pragma unroll
  for (int j = 0; j < 16; ++j) acc[j] = 0.f;
  const float* wp = W + oc * 192;
  for (int i = 0; i < 64; ++i) {
    float w0 = wp[i * 3], w1 = wp[i * 3 + 1], w2 = wp[i * 3 + 2];
    float4 buf[6];
    const float4* xp = reinterpret_cast<const float4*>(&xl[i * 136 + h0]);
#pragma unroll
    for (int r = 0; r < 6; ++r) buf[r] = xp[r];
    const float* bf = reinterpret_cast<const float*>(buf);
#pragma unroll
    for (int j = 0; j < 16; ++j)
      acc[j] += w0 * bf[3 + j] + w1 * bf[4 + j] + w2 * bf[5 + j];
  }
  float bia = bias[oc], sc = bnx[oc] * BNR, bt = bnx[32 + oc];
  float* outp = O + (size_t)b * 4096 + oc * 128 + h0;
#pragma unroll
  for (int j = 0; j < 16; ++j) acc[j] = fmaxf(0.f, sc * (acc[j] + bia) + bt);
#pragma unroll
  for (int j = 0; j < 4; ++j)
    *reinterpret_cast<float4*>(outp + 4 * j) =
        make_float4(acc[4 * j], acc[4 * j + 1], acc[4 * j + 2], acc[4 * j + 3]);
}

// ---- fxt: [512,4096] @ [4096,128], K-split 8 ways for parallelism ----
__global__ __launch_bounds__(128) void k_fxt_part(const float* __restrict__ P, const float* __restrict__ W,
                                                  float* __restrict__ part) {
  __shared__ float pl[8 * 512];
  int bblk = blockIdx.x >> 3, kc = blockIdx.x & 7;
  int b0 = bblk * 8, tid = threadIdx.x;
  for (int i = tid; i < 8 * 512; i += 128) {
    int bb = i >> 9, k = i & 511;
    pl[i] = P[(size_t)(b0 + bb) * 4096 + kc * 512 + k];
  }
  __syncthreads();
  float acc[8] = {};
  const float* wp = W + (size_t)kc * 512 * 128 + tid;
  for (int k = 0; k < 512; ++k) {
    float w = wp[(size_t)k * 128];
#pragma unroll
    for (int bb = 0; bb < 8; ++bb) acc[bb] += pl[bb * 512 + k] * w;
  }
#pragma unroll
  for (int bb = 0; bb < 8; ++bb)
    part[((size_t)kc * 512 + b0 + bb) * 128 + tid] = acc[bb];
}

// xt = bn6(relu(sum_kc part + fxt_b))   (bn AFTER relu)
__global__ __launch_bounds__(256) void k_fxt_red(const float* __restrict__ part, const float* __restrict__ bias,
                                                 const float* __restrict__ bn, float* __restrict__ xt) {
  int idx = blockIdx.x * 256 + threadIdx.x;  // 512*128
  int j = idx & 127;
  float s = 0.f;
#pragma unroll
  for (int kc = 0; kc < 8; ++kc) s += part[(size_t)kc * 65536 + idx];
  xt[idx] = bn[j] * BNR * fmaxf(0.f, s + bias[j]) + bn[128 + j];
}

// xc1 = bn7(relu([g|xt] @ fc1W + fc1b)); grid 512 = (bblk 0..127)x(jb 0..3)
__global__ __launch_bounds__(256) void k_fc1(const float* __restrict__ g, const float* __restrict__ xt,
                                             const float* __restrict__ W, const float* __restrict__ bias,
                                             const float* __restrict__ bn, float* __restrict__ out) {
  __shared__ float al[4 * 256];
  int bblk = blockIdx.x >> 2, jb = blockIdx.x & 3;
  int b0 = bblk * 4, tid = threadIdx.x;
  int j = jb * 256 + tid;
  for (int i = tid; i < 4 * 256; i += 256) {
    int bb = i >> 8, c = i & 255;
    al[i] = (c < 128) ? g[(b0 + bb) * 128 + c] : xt[(b0 + bb) * 128 + c - 128];
  }
  __syncthreads();
  float acc[4] = {};
  for (int i = 0; i < 256; ++i) {
    float w = W[(size_t)i * 1024 + j];
#pragma unroll
    for (int bb = 0; bb < 4; ++bb) acc[bb] += al[bb * 256 + i] * w;
  }
  float bi = bias[j], sc = bn[j] * BNR, bt = bn[1024 + j];
#pragma unroll
  for (int bb = 0; bb < 4; ++bb)
    out[(size_t)(b0 + bb) * 1024 + j] = sc * fmaxf(0.f, acc[bb] + bi) + bt;
}

// xc2 = bn8(relu(xc1 @ fc2W + fc2b)); grid 256 = (bblk 0..127)x(jb 0..1)
__global__ __launch_bounds__(256) void k_fc2(const float* __restrict__ xc1, const float* __restrict__ W,
                                             const float* __restrict__ bias, const float* __restrict__ bn,
                                             float* __restrict__ out) {
  __shared__ float al[4 * 1024];
  int bblk = blockIdx.x >> 1, jb = blockIdx.x & 1;
  int b0 = bblk * 4, tid = threadIdx.x;
  int j = jb * 256 + tid;
  for (int i = tid; i < 4 * 1024; i += 256)
    al[i] = xc1[(size_t)(b0 + (i >> 10)) * 1024 + (i & 1023)];
  __syncthreads();
  float acc[4] = {};
  for (int i = 0; i < 1024; ++i) {
    float w = W[(size_t)i * 512 + j];
#pragma unroll
    for (int bb = 0; bb < 4; ++bb) acc[bb] += al[bb * 1024 + i] * w;
  }
  float bi = bias[j], sc = bn[j] * BNR, bt = bn[512 + j];
#pragma unroll
  for (int bb = 0; bb < 4; ++bb)
    out[(size_t)(b0 + bb) * 512 + j] = sc * fmaxf(0.f, acc[bb] + bi) + bt;
}

__global__ __launch_bounds__(256) void k_out(const float* __restrict__ xc2, const float* __restrict__ W,
                                             const float* __restrict__ ob, float* __restrict__ out) {
  __shared__ float red[4];
  int b = blockIdx.x, tid = threadIdx.x;
  float v = xc2[(size_t)b * 512 + tid] * W[tid] + xc2[(size_t)b * 512 + 256 + tid] * W[256 + tid];
  v = wave_red_sum(v);
  int wave = tid >> 6, lane = tid & 63;
  if (lane == 0) red[wave] = v;
  __syncthreads();
  if (tid == 0) out[b] = red[0] + red[1] + red[2] + red[3] + ob[0];
}

extern "C" void kernel_launch(void* const* d_in, const int* in_sizes, int n_in,
                              void* d_out, int out_size, void* d_ws, size_t ws_size,
                              hipStream_t stream) {
  (void)in_sizes; (void)n_in; (void)out_size; (void)ws_size;
  const float* x      = (const float*)d_in[0];
  const int*   eidx   = (const int*)d_in[1];
  const int*   src    = eidx;
  const int*   dst    = eidx + N_EDGES;
  const int*   target = (const int*)d_in[3];
  const float* W1 = (const float*)d_in[4];  const float* b1 = (const float*)d_in[5];
  const float* bn1 = (const float*)d_in[6]; const float* Wp1 = (const float*)d_in[7];
  const float* bp1 = (const float*)d_in[8];
  const float* W2 = (const float*)d_in[9];  const float* b2 = (const float*)d_in[10];
  const float* bn2 = (const float*)d_in[11]; const float* Wp2 = (const float*)d_in[12];
  const float* bp2 = (const float*)d_in[13];
  const float* W3 = (const float*)d_in[14]; const float* b3 = (const float*)d_in[15];
  const float* bn3 = (const float*)d_in[16]; const float* Wp3 = (const float*)d_in[17];
  const float* bp3 = (const float*)d_in[18];
  const float* fcg1_W = (const float*)d_in[19]; const float* fcg1_b = (const float*)d_in[20];
  const float* bn4 = (const float*)d_in[21];
  const float* emb = (const float*)d_in[22];
  const float* c1W = (const float*)d_in[23]; const float* c1b = (const float*)d_in[24];
  const float* bnx1 = (const float*)d_in[25];
  const float* c2W = (const float*)d_in[26]; const float* c2b = (const float*)d_in[27];
  const float* bnx2 = (const float*)d_in[28];
  const float* c3W = (const float*)d_in[29]; const float* c3b = (const float*)d_in[30];
  const float* bnx3 = (const float*)d_in[31];
  const float* fxt_W = (const float*)d_in[32]; const float* fxt_b = (const float*)d_in[33];
  const float* bn6 = (const float*)d_in[34];
  const float* fc1W = (const float*)d_in[35]; const float* fc1b = (const float*)d_in[36];
  const float* bn7 = (const float*)d_in[37];
  const float* fc2W = (const float*)d_in[38]; const float* fc2b = (const float*)d_in[39];
  const float* bn8 = (const float*)d_in[40];
  const float* outW = (const float*)d_in[41]; const float* outb = (const float*)d_in[42];

  char* ws = (char*)d_ws;
  size_t off = 0;
  auto alloc = [&](size_t bytes) -> void* {
    void* p = ws + off;
    off += (bytes + 255) & ~(size_t)255;
    return p;
  };
  float* dis   = (float*)alloc((size_t)N_NODES * 4);
  int*   cnt   = (int*)alloc((size_t)N_NODES * 4);
  int*   cursor= (int*)alloc((size_t)N_NODES * 4);
  int*   offs  = (int*)alloc((size_t)N_NODES * 4);
  int*   bsum  = (int*)alloc(1024);
  int*   csr   = (int*)alloc((size_t)N_EDGES * 4);
  float* cf    = (float*)alloc((size_t)N_EDGES * 4);
  float* h_a   = (float*)alloc((size_t)N_NODES * NF * 4);   // region; holds bf16 h rows (39 uints)
  float* h_b   = (float*)alloc((size_t)N_NODES * NF * 4);
  float* tbuf  = (float*)alloc((size_t)N_NODES * NF * 4);   // region; holds fp8 t (128B rows = 16.8MB)
  float* gate  = (float*)alloc((size_t)N_NODES * 4);
  float* spre  = (float*)alloc((size_t)N_NODES * 4);
  float* xsum  = (float*)alloc(512 * 156 * 4);
  float* gbuf  = (float*)alloc(512 * 128 * 4);
  float* xt    = (float*)alloc(512 * 128 * 4);
  float* xc1   = (float*)alloc(512 * 1024 * 4);
  float* xc2   = (float*)alloc(512 * 512 * 4);
  unsigned char*  t8  = (unsigned char*)tbuf;
  unsigned short* t16 = (unsigned short*)tbuf;
  unsigned* ha_u = (unsigned*)h_a;  unsigned short* ha_s = (unsigned short*)h_a;
  unsigned* hb_u = (unsigned*)h_b;  unsigned short* hb_s = (unsigned short*)h_b;
  // protein-branch aliases (GNN big buffers are dead by then)
  float* O1 = h_a;                      // 512*128*128 = 33.5 MB <= 40.9 MB
  float* O2 = h_b;                      // 512*64*128  = 16.8 MB
  float* Wt = tbuf;                     // 1000*384    = 1.54 MB
  float* P  = tbuf + 5242880;           // +20 MB: past fp8 t region; 512*32*128 = 8.4 MB (fits 40.9)
  float* fxt_part = h_a;                // 8*512*128 = 2 MB (O1 dead after conv2)

  hipMemsetAsync(cnt, 0, (size_t)N_NODES * 4, stream);
  hipMemsetAsync(cursor, 0, (size_t)N_NODES * 4, stream);

  k_count<<<N_EDGES / 256, 256, 0, stream>>>(dst, cnt);
  k_dis<<<N_NODES / 256, 256, 0, stream>>>(cnt, dis);
  k_scan1<<<N_NODES / 512, 512, 0, stream>>>(cnt, offs, bsum);
  k_scan2<<<1, 256, 0, stream>>>(bsum);
  k_scan3<<<N_NODES / 512, 512, 0, stream>>>(offs, bsum);
  k_fill<<<N_EDGES / 256, 256, 0, stream>>>(src, dst, offs, cursor, dis, csr, cf);

  // layer 1
  k_gemm_f32<<<N_NODES / 64, 256, 0, stream>>>(x, W1, t8);
  k_agg<<<N_NODES / 4, 256, 0, stream>>>(t16, offs, cnt, csr, cf, dis, b1, bn1, Wp1, ha_u, spre);
  k_gate<<<N_NODES / 256, 256, 0, stream>>>(spre, offs, cnt, csr, cf, dis, bp1, gate);
  k_readout<<<NB, 128, 0, stream>>>(ha_s, gate, xsum, 0);
  // layer 2
  k_gemm_bf16<<<N_NODES / 64, 256, 0, stream>>>(ha_s, gate, W2, t8);
  k_agg<<<N_NODES / 4, 256, 0, stream>>>(t16, offs, cnt, csr, cf, dis, b2, bn2, Wp2, hb_u, spre);
  k_gate<<<N_NODES / 256, 256, 0, stream>>>(spre, offs, cnt, csr, cf, dis, bp2, gate);
  k_readout<<<NB, 128, 0, stream>>>(hb_s, gate, xsum, 1);
  // layer 3
  k_gemm_bf16<<<N_NODES / 64, 256, 0, stream>>>(hb_s, gate, W3, t8);
  k_agg<<<N_NODES / 4, 256, 0, stream>>>(t16, offs, cnt, csr, cf, dis, b3, bn3, Wp3, ha_u, spre);
  k_gate<<<N_NODES / 256, 256, 0, stream>>>(spre, offs, cnt, csr, cf, dis, bp3, gate);
  k_readout<<<NB, 128, 0, stream>>>(ha_s, gate, xsum, 1);

  k_fcg<<<NB, 128, 0, stream>>>(xsum, fcg1_W, fcg1_b, bn4, gbuf);

  // protein branch (reuses h_a/h_b/tbuf regions — all GNN reads complete above)
  k_transpose_w<<<1500, 256, 0, stream>>>(c1W, Wt);
  k_conv1<<<NB, 512, 0, stream>>>(Wt, target, emb, c1b, bnx1, O1);
  k_conv2<<<NB, 256, 0, stream>>>(O1, c2W, c2b, bnx2, O2);
  k_conv3<<<NB, 256, 0, stream>>>(O2, c3W, c3b, bnx3, P);
  // O1 (h_a) is dead after conv2 -> reuse for fxt partials
  k_fxt_part<<<512, 128, 0, stream>>>(P, fxt_W, fxt_part);
  k_fxt_red<<<256, 256, 0, stream>>>(fxt_part, fxt_b, bn6, xt);

  k_fc1<<<512, 256, 0, stream>>>(gbuf, xt, fc1W, fc1b, bn7, xc1);
  k_fc2<<<256, 256, 0, stream>>>(xc1, fc2W, fc2b, bn8, xc2);
  k_out<<<NB, 256, 0, stream>>>(xc2, outW, outb, (float*)d_out);
}